// Round 3
// baseline (215.157 us; speedup 1.0000x reference)
//
#include <hip/hip_runtime.h>
#include <hip/hip_bf16.h>

// Triangle attention (starting node), b=1, n=256, d=128, H=4, DH=32.
// Round 2: swapped-QK^T attention, bias-as-accumulator-init, barrier-free
// main loop, vectorized P roundtrip. GEMMs unchanged from round 1.

#define NP  256
#define DD  128

typedef short bf16x8 __attribute__((ext_vector_type(8)));
typedef float f32x4  __attribute__((ext_vector_type(4)));

__device__ __forceinline__ float bf2f(ushort u) {
    union { unsigned int v; float f; } c; c.v = ((unsigned int)u) << 16; return c.f;
}
__device__ __forceinline__ ushort f2bf(float f) {
    union { float f; unsigned int v; } c; c.f = f;
    unsigned int x = c.v;
    return (ushort)((x + 0x7FFFu + ((x >> 16) & 1u)) >> 16);  // RNE
}
__device__ __forceinline__ unsigned int packbf(float a, float b) {
    __hip_bfloat162 t = __float22bfloat162_rn(make_float2(a, b));  // a -> low
    union { __hip_bfloat162 h; unsigned int u; } c; c.h = t; return c.u;
}
__device__ __forceinline__ f32x4 mfma16(bf16x8 a, bf16x8 b, f32x4 c) {
    return __builtin_amdgcn_mfma_f32_16x16x32_bf16(a, b, c, 0, 0, 0);
}

#define NEGV (-3.4028234663852886e38f)
#define SCALE 0.17677669529663687f

// ---------------- K0: W -> bf16, transposed (N-major, K-contiguous) --------
__global__ __launch_bounds__(256) void k_wconv(
    const float* __restrict__ Wqkv, const float* __restrict__ Wg,
    const float* __restrict__ Wout, ushort* __restrict__ WT,
    ushort* __restrict__ WoT)
{
    int idx = blockIdx.x * 256 + threadIdx.x;   // grid 320 -> 81920
    if (idx < 65536) {
        int n = idx >> 7, k = idx & 127;
        float v = (n < 384) ? Wqkv[(size_t)k * 384 + n]
                            : Wg[(size_t)k * 128 + (n - 384)];
        WT[idx] = f2bf(v);
    } else {
        int i2 = idx - 65536;
        int c = i2 >> 7, e = i2 & 127;
        WoT[i2] = f2bf(Wout[(size_t)e * 128 + c]);
    }
}

// ---------------- K1: LayerNorm -> x bf16, + bias GEMV (f32 [h][p]) --------
__global__ __launch_bounds__(256) void k_ln(
    const float* __restrict__ edges, const float* __restrict__ gamma,
    const float* __restrict__ beta,  const float* __restrict__ Wb,
    ushort* __restrict__ Xb, float* __restrict__ Bo)
{
    __shared__ float xs[64][132];
    const int tid = threadIdx.x, w = tid >> 6, lane = tid & 63;
    const int p0 = blockIdx.x * 64;
    const float g0 = gamma[lane], g1 = gamma[lane + 64];
    const float b0 = beta[lane],  b1 = beta[lane + 64];
    for (int pp = 0; pp < 16; ++pp) {
        const int row = w * 16 + pp;
        const float* ep = edges + (size_t)(p0 + row) * DD;
        float e0 = ep[lane], e1 = ep[lane + 64];
        float s = e0 + e1;
        #pragma unroll
        for (int off = 1; off < 64; off <<= 1) s += __shfl_xor(s, off);
        float mu = s * 0.0078125f;
        float d0 = e0 - mu, d1 = e1 - mu;
        float ss = d0 * d0 + d1 * d1;
        #pragma unroll
        for (int off = 1; off < 64; off <<= 1) ss += __shfl_xor(ss, off);
        float rstd = rsqrtf(ss * 0.0078125f + 1e-5f);
        xs[row][lane]      = d0 * rstd * g0 + b0;
        xs[row][lane + 64] = d1 * rstd * g1 + b1;
    }
    __syncthreads();
    #pragma unroll
    for (int pass = 0; pass < 8; ++pass) {
        int idx = pass * 256 + tid;
        int r = idx >> 5, c = (idx & 31) * 4;
        ushort4 o;
        o.x = f2bf(xs[r][c + 0]); o.y = f2bf(xs[r][c + 1]);
        o.z = f2bf(xs[r][c + 2]); o.w = f2bf(xs[r][c + 3]);
        *reinterpret_cast<ushort4*>(&Xb[(size_t)(p0 + r) * DD + c]) = o;
    }
    // bias = x @ Wb, f32, layout Bo[h][p] (p = j*256 + k)
    {
        const int r = tid >> 2, hh = tid & 3;
        float acc = 0.f;
        for (int e = 0; e < DD; ++e) acc += xs[r][e] * Wb[e * 4 + hh];
        Bo[(size_t)hh * 65536 + p0 + r] = acc;
    }
}

// ---------------- K2: x @ [Wqkv|Wg] via MFMA; scale folded into Q ----------
__global__ __launch_bounds__(256) void k_gemm_qkvg(
    const ushort* __restrict__ Xb, const ushort* __restrict__ WT,
    const float* __restrict__ bg,
    ushort* __restrict__ Qo, ushort* __restrict__ Ko,
    ushort* __restrict__ Vo, ushort* __restrict__ Go)
{
    __shared__ __align__(16) ushort As[64][136];
    __shared__ __align__(16) ushort Bs[128][136];
    const int tid = threadIdx.x;
    const int p0 = blockIdx.x * 64, n0 = blockIdx.y * 128;
    #pragma unroll
    for (int it = 0; it < 4; ++it) {
        int idx = it * 256 + tid;
        int r = idx >> 4, c = (idx & 15) * 8;
        *reinterpret_cast<uint4*>(&As[r][c]) =
            *reinterpret_cast<const uint4*>(&Xb[(size_t)(p0 + r) * DD + c]);
    }
    #pragma unroll
    for (int it = 0; it < 8; ++it) {
        int idx = it * 256 + tid;
        int r = idx >> 4, c = (idx & 15) * 8;
        *reinterpret_cast<uint4*>(&Bs[r][c]) =
            *reinterpret_cast<const uint4*>(&WT[(size_t)(n0 + r) * DD + c]);
    }
    __syncthreads();
    const int w = tid >> 6, lane = tid & 63;
    const int wm = w >> 1, wn = w & 1;
    const int lr = lane & 15, lg = lane >> 4;
    const f32x4 zz = {0.f, 0.f, 0.f, 0.f};
    f32x4 acc[2][4];
    #pragma unroll
    for (int m = 0; m < 2; ++m)
        #pragma unroll
        for (int n = 0; n < 4; ++n) acc[m][n] = zz;
    #pragma unroll
    for (int kk = 0; kk < 4; ++kk) {
        bf16x8 a0 = *reinterpret_cast<const bf16x8*>(&As[wm * 32 + lr][kk * 32 + lg * 8]);
        bf16x8 a1 = *reinterpret_cast<const bf16x8*>(&As[wm * 32 + 16 + lr][kk * 32 + lg * 8]);
        #pragma unroll
        for (int n = 0; n < 4; ++n) {
            bf16x8 b = *reinterpret_cast<const bf16x8*>(&Bs[wn * 64 + n * 16 + lr][kk * 32 + lg * 8]);
            acc[0][n] = mfma16(a0, b, acc[0][n]);
            acc[1][n] = mfma16(a1, b, acc[1][n]);
        }
    }
    const int seg = n0 >> 7;   // 0:q 1:k 2:v 3:g
    #pragma unroll
    for (int n = 0; n < 4; ++n) {
        const int cc = (n0 & 127) + wn * 64 + n * 16 + lr;
        const float bgv = (seg == 3) ? bg[cc] : 0.f;
        #pragma unroll
        for (int m = 0; m < 2; ++m) {
            #pragma unroll
            for (int r = 0; r < 4; ++r) {
                const int p = p0 + wm * 32 + m * 16 + lg * 4 + r;
                const float v = acc[m][n][r];
                const size_t off = (size_t)p * DD + cc;
                if (seg == 0)      Qo[off] = f2bf(v * SCALE);
                else if (seg == 1) Ko[off] = f2bf(v);
                else if (seg == 2) Vo[off] = f2bf(v);
                else Go[off] = f2bf(1.0f / (1.0f + __expf(-(v + bgv))));
            }
        }
    }
}

// ---------------- K3: attention, swapped QK^T, barrier-free main loop ------
// grid 1024 (= 256 i * 4 h) x 256 threads (4 waves).
__global__ __launch_bounds__(256, 3) void k_attn3(
    const ushort* __restrict__ Qw, const ushort* __restrict__ Kw,
    const ushort* __restrict__ Vw, const ushort* __restrict__ Gw,
    const float* __restrict__ Bo,  const int* __restrict__ mask,
    ushort* __restrict__ OPre)
{
    __shared__ __align__(16) ushort Vt[32][264];       // V^T [d][k], 16.9 KB
    __shared__ __align__(16) ushort Pl[4][16][136];    // per-wave P chunk, 17.4 KB
    const int tid = threadIdx.x, w = tid >> 6, lane = tid & 63;
    const int lr = lane & 15, lg = lane >> 4;
    const int i = blockIdx.x >> 2, h = blockIdx.x & 3;
    const int ib = i * NP;
    const size_t base = (size_t)ib * DD + h * 32;

    // stage V^T into LDS (one-time)
    #pragma unroll
    for (int it = 0; it < 8; ++it) {
        int idx = it * 256 + tid;
        int k = idx >> 3, dc = (idx & 7) * 4;
        ushort4 v = *reinterpret_cast<const ushort4*>(&Vw[base + (size_t)k * DD + dc]);
        Vt[dc + 0][k] = v.x; Vt[dc + 1][k] = v.y;
        Vt[dc + 2][k] = v.z; Vt[dc + 3][k] = v.w;
    }
    __syncthreads();

    const float* bias_h = Bo + (size_t)h * 65536;
    const f32x4 zz = {0.f, 0.f, 0.f, 0.f};

    for (int jt = 0; jt < 4; ++jt) {
        const int jb = jt * 64 + w * 16;
        const int jq = jb + lr;             // this lane's softmax row
        // Q B-frag (global, L2-hit)
        bf16x8 q = *reinterpret_cast<const bf16x8*>(&Qw[base + (size_t)jq * DD + lg * 8]);
        // scores: accumulator initialized with bias (f32, vectorized)
        f32x4 s[16];
        const float* bp = bias_h + (size_t)jq * 256 + 4 * lg;
        #pragma unroll
        for (int fn = 0; fn < 16; ++fn)
            s[fn] = *reinterpret_cast<const f32x4*>(bp + fn * 16);
        #pragma unroll
        for (int fn = 0; fn < 16; ++fn) {
            bf16x8 a = *reinterpret_cast<const bf16x8*>(
                &Kw[base + (size_t)(fn * 16 + lr) * DD + lg * 8]);
            s[fn] = mfma16(a, q, s[fn]);    // S^T[k][j]
        }
        // softmax over k for row jq (4-lane group: xor 16, 32)
        float mx = -3.402823466e38f;
        #pragma unroll
        for (int fn = 0; fn < 16; ++fn) {
            float m01 = fmaxf(s[fn][0], s[fn][1]);
            float m23 = fmaxf(s[fn][2], s[fn][3]);
            mx = fmaxf(mx, fmaxf(m01, m23));
        }
        mx = fmaxf(mx, __shfl_xor(mx, 16));
        mx = fmaxf(mx, __shfl_xor(mx, 32));
        float sum = 0.f;
        #pragma unroll
        for (int fn = 0; fn < 16; ++fn) {
            #pragma unroll
            for (int r = 0; r < 4; ++r) {
                float e = __expf(s[fn][r] - mx);
                s[fn][r] = e; sum += e;
            }
        }
        sum += __shfl_xor(sum, 16);
        sum += __shfl_xor(sum, 32);
        const bool masked = (mask[ib + jq] == 0);
        const float inv = masked ? 1.0f : (1.0f / sum);  // normalization deferred

        // PV in 2 chunks of 128 keys; P stays wave-private (no barriers)
        f32x4 o0 = zz, o1 = zz;
        #pragma unroll
        for (int c = 0; c < 2; ++c) {
            #pragma unroll
            for (int fnl = 0; fnl < 8; ++fnl) {
                const int fn = c * 8 + fnl;
                unsigned int w0 = packbf(s[fn][0], s[fn][1]);
                unsigned int w1 = packbf(s[fn][2], s[fn][3]);
                if (masked) { w0 = 0x3B803B80u; w1 = 0x3B803B80u; }  // 1/256
                uint2 pw; pw.x = w0; pw.y = w1;
                *reinterpret_cast<uint2*>(&Pl[w][lr][fnl * 16 + 4 * lg]) = pw;
            }
            #pragma unroll
            for (int ks = 0; ks < 4; ++ks) {
                bf16x8 pa = *reinterpret_cast<const bf16x8*>(&Pl[w][lr][ks * 32 + lg * 8]);
                bf16x8 v0 = *reinterpret_cast<const bf16x8*>(&Vt[lr][c * 128 + ks * 32 + lg * 8]);
                bf16x8 v1 = *reinterpret_cast<const bf16x8*>(&Vt[16 + lr][c * 128 + ks * 32 + lg * 8]);
                o0 = mfma16(pa, v0, o0);
                o1 = mfma16(pa, v1, o1);
            }
        }
        // epilogue: rows j = jb + 4*lg + r, cols d = lr / 16+lr
        #pragma unroll
        for (int r = 0; r < 4; ++r) {
            const int j = jb + 4 * lg + r;
            const bool mk = (mask[ib + j] == 0);
            const float iv = __shfl(inv, 4 * lg + r);
            const size_t off = base + (size_t)j * DD;
            const float g0 = mk ? NEGV : bf2f(Gw[off + lr]);
            const float g1 = mk ? NEGV : bf2f(Gw[off + 16 + lr]);
            OPre[off + lr]      = f2bf(o0[r] * iv * g0);
            OPre[off + 16 + lr] = f2bf(o1[r] * iv * g1);
        }
    }
}

// ---------------- K4: out = OPre @ Wout + bout (MFMA) ----------------------
__global__ __launch_bounds__(256) void k_gemm_out(
    const ushort* __restrict__ OPre, const ushort* __restrict__ WoT,
    const float* __restrict__ bout, float* __restrict__ out)
{
    __shared__ __align__(16) ushort As[64][136];
    __shared__ __align__(16) ushort Bs[128][136];
    const int tid = threadIdx.x;
    const int p0 = blockIdx.x * 64;
    #pragma unroll
    for (int it = 0; it < 4; ++it) {
        int idx = it * 256 + tid;
        int r = idx >> 4, c = (idx & 15) * 8;
        *reinterpret_cast<uint4*>(&As[r][c]) =
            *reinterpret_cast<const uint4*>(&OPre[(size_t)(p0 + r) * DD + c]);
    }
    #pragma unroll
    for (int it = 0; it < 8; ++it) {
        int idx = it * 256 + tid;
        int r = idx >> 4, c = (idx & 15) * 8;
        *reinterpret_cast<uint4*>(&Bs[r][c]) =
            *reinterpret_cast<const uint4*>(&WoT[(size_t)r * DD + c]);
    }
    __syncthreads();
    const int w = tid >> 6, lane = tid & 63;
    const int wm = w >> 1, wn = w & 1;
    const int lr = lane & 15, lg = lane >> 4;
    const f32x4 zz = {0.f, 0.f, 0.f, 0.f};
    f32x4 acc[2][4];
    #pragma unroll
    for (int m = 0; m < 2; ++m)
        #pragma unroll
        for (int n = 0; n < 4; ++n) acc[m][n] = zz;
    #pragma unroll
    for (int kk = 0; kk < 4; ++kk) {
        bf16x8 a0 = *reinterpret_cast<const bf16x8*>(&As[wm * 32 + lr][kk * 32 + lg * 8]);
        bf16x8 a1 = *reinterpret_cast<const bf16x8*>(&As[wm * 32 + 16 + lr][kk * 32 + lg * 8]);
        #pragma unroll
        for (int n = 0; n < 4; ++n) {
            bf16x8 b = *reinterpret_cast<const bf16x8*>(&Bs[wn * 64 + n * 16 + lr][kk * 32 + lg * 8]);
            acc[0][n] = mfma16(a0, b, acc[0][n]);
            acc[1][n] = mfma16(a1, b, acc[1][n]);
        }
    }
    #pragma unroll
    for (int n = 0; n < 4; ++n) {
        const int c = wn * 64 + n * 16 + lr;
        const float bo = bout[c];
        #pragma unroll
        for (int m = 0; m < 2; ++m) {
            #pragma unroll
            for (int r = 0; r < 4; ++r) {
                const int p = p0 + wm * 32 + m * 16 + lg * 4 + r;
                out[(size_t)p * DD + c] = acc[m][n][r] + bo;
            }
        }
    }
}

extern "C" void kernel_launch(void* const* d_in, const int* in_sizes, int n_in,
                              void* d_out, int out_size, void* d_ws, size_t ws_size,
                              hipStream_t stream) {
    const float* edges = (const float*)d_in[0];
    const int*   mask  = (const int*)d_in[1];
    const float* gamma = (const float*)d_in[2];
    const float* beta  = (const float*)d_in[3];
    const float* Wqkv  = (const float*)d_in[4];
    const float* Wb    = (const float*)d_in[5];
    const float* Wg    = (const float*)d_in[6];
    const float* bg    = (const float*)d_in[7];
    const float* Wout  = (const float*)d_in[8];
    const float* bout  = (const float*)d_in[9];
    float* out = (float*)d_out;

    char* ws = (char*)d_ws;
    ushort* Xb  = (ushort*)(ws);
    ushort* Qw  = (ushort*)(ws + 1u * 16777216u);
    ushort* Kw  = (ushort*)(ws + 2u * 16777216u);
    ushort* Vw  = (ushort*)(ws + 3u * 16777216u);
    ushort* Gw  = (ushort*)(ws + 4u * 16777216u);
    float*  Bo  = (float*) (ws + 5u * 16777216u);             // 1 MiB f32
    ushort* WT  = (ushort*)(ws + 5u * 16777216u + 1048576u);  // 128 KiB
    ushort* WoT = (ushort*)(ws + 5u * 16777216u + 1048576u + 131072u); // 32 KiB
    ushort* OPre = Xb;   // Xb dead after k_gemm_qkvg

    k_wconv<<<dim3(320), dim3(256), 0, stream>>>(Wqkv, Wg, Wout, WT, WoT);
    k_ln<<<dim3(1024), dim3(256), 0, stream>>>(edges, gamma, beta, Wb, Xb, Bo);
    k_gemm_qkvg<<<dim3(1024, 4), dim3(256), 0, stream>>>(Xb, WT, bg, Qw, Kw, Vw, Gw);
    k_attn3<<<dim3(1024), dim3(256), 0, stream>>>(Qw, Kw, Vw, Gw, Bo, mask, OPre);
    k_gemm_out<<<dim3(1024), dim3(256), 0, stream>>>(OPre, WoT, bout, out);
}

// Round 4
// 206.300 us; speedup vs baseline: 1.0429x; 1.0429x over previous
//
#include <hip/hip_runtime.h>
#include <hip/hip_bf16.h>

// Triangle attention (starting node), b=1, n=256, d=128, H=4, DH=32.
// Round 3: swapped-QK^T attention restored onto round-1 LDS-resident
// structure; bf16 bias accum-init; 46.6KB LDS -> 3 blocks/CU; no barriers
// in the j-loop. GEMMs unchanged.

#define NP  256
#define DD  128

typedef short bf16x8 __attribute__((ext_vector_type(8)));
typedef float f32x4  __attribute__((ext_vector_type(4)));

__device__ __forceinline__ float bf2f(ushort u) {
    union { unsigned int v; float f; } c; c.v = ((unsigned int)u) << 16; return c.f;
}
__device__ __forceinline__ ushort f2bf(float f) {
    union { float f; unsigned int v; } c; c.f = f;
    unsigned int x = c.v;
    return (ushort)((x + 0x7FFFu + ((x >> 16) & 1u)) >> 16);  // RNE
}
__device__ __forceinline__ unsigned int packbf(float a, float b) {
    __hip_bfloat162 t = __float22bfloat162_rn(make_float2(a, b));  // a -> low
    union { __hip_bfloat162 h; unsigned int u; } c; c.h = t; return c.u;
}
__device__ __forceinline__ f32x4 mfma16(bf16x8 a, bf16x8 b, f32x4 c) {
    return __builtin_amdgcn_mfma_f32_16x16x32_bf16(a, b, c, 0, 0, 0);
}

#define NEGV (-3.4028234663852886e38f)
#define SCALE 0.17677669529663687f

// ---------------- K0: W -> bf16, transposed (N-major, K-contiguous) --------
__global__ __launch_bounds__(256) void k_wconv(
    const float* __restrict__ Wqkv, const float* __restrict__ Wg,
    const float* __restrict__ Wout, ushort* __restrict__ WT,
    ushort* __restrict__ WoT)
{
    int idx = blockIdx.x * 256 + threadIdx.x;   // grid 320 -> 81920
    if (idx < 65536) {
        int n = idx >> 7, k = idx & 127;
        float v = (n < 384) ? Wqkv[(size_t)k * 384 + n]
                            : Wg[(size_t)k * 128 + (n - 384)];
        WT[idx] = f2bf(v);
    } else {
        int i2 = idx - 65536;
        int c = i2 >> 7, e = i2 & 127;
        WoT[i2] = f2bf(Wout[(size_t)e * 128 + c]);
    }
}

// ---------------- K1: LayerNorm -> x bf16, + bias GEMV (bf16 [h][p]) -------
__global__ __launch_bounds__(256) void k_ln(
    const float* __restrict__ edges, const float* __restrict__ gamma,
    const float* __restrict__ beta,  const float* __restrict__ Wb,
    ushort* __restrict__ Xb, ushort* __restrict__ Bo)
{
    __shared__ float xs[64][132];
    const int tid = threadIdx.x, w = tid >> 6, lane = tid & 63;
    const int p0 = blockIdx.x * 64;
    const float g0 = gamma[lane], g1 = gamma[lane + 64];
    const float b0 = beta[lane],  b1 = beta[lane + 64];
    for (int pp = 0; pp < 16; ++pp) {
        const int row = w * 16 + pp;
        const float* ep = edges + (size_t)(p0 + row) * DD;
        float e0 = ep[lane], e1 = ep[lane + 64];
        float s = e0 + e1;
        #pragma unroll
        for (int off = 1; off < 64; off <<= 1) s += __shfl_xor(s, off);
        float mu = s * 0.0078125f;
        float d0 = e0 - mu, d1 = e1 - mu;
        float ss = d0 * d0 + d1 * d1;
        #pragma unroll
        for (int off = 1; off < 64; off <<= 1) ss += __shfl_xor(ss, off);
        float rstd = rsqrtf(ss * 0.0078125f + 1e-5f);
        xs[row][lane]      = d0 * rstd * g0 + b0;
        xs[row][lane + 64] = d1 * rstd * g1 + b1;
    }
    __syncthreads();
    #pragma unroll
    for (int pass = 0; pass < 8; ++pass) {
        int idx = pass * 256 + tid;
        int r = idx >> 5, c = (idx & 31) * 4;
        ushort4 o;
        o.x = f2bf(xs[r][c + 0]); o.y = f2bf(xs[r][c + 1]);
        o.z = f2bf(xs[r][c + 2]); o.w = f2bf(xs[r][c + 3]);
        *reinterpret_cast<ushort4*>(&Xb[(size_t)(p0 + r) * DD + c]) = o;
    }
    // bias = x @ Wb, bf16, layout Bo[h][p] (p = j*256 + k)
    {
        const int r = tid >> 2, hh = tid & 3;
        float acc = 0.f;
        for (int e = 0; e < DD; ++e) acc += xs[r][e] * Wb[e * 4 + hh];
        Bo[(size_t)hh * 65536 + p0 + r] = f2bf(acc);
    }
}

// ---------------- K2: x @ [Wqkv|Wg] via MFMA; scale folded into Q ----------
__global__ __launch_bounds__(256) void k_gemm_qkvg(
    const ushort* __restrict__ Xb, const ushort* __restrict__ WT,
    const float* __restrict__ bg,
    ushort* __restrict__ Qo, ushort* __restrict__ Ko,
    ushort* __restrict__ Vo, ushort* __restrict__ Go)
{
    __shared__ __align__(16) ushort As[64][136];
    __shared__ __align__(16) ushort Bs[128][136];
    const int tid = threadIdx.x;
    const int p0 = blockIdx.x * 64, n0 = blockIdx.y * 128;
    #pragma unroll
    for (int it = 0; it < 4; ++it) {
        int idx = it * 256 + tid;
        int r = idx >> 4, c = (idx & 15) * 8;
        *reinterpret_cast<uint4*>(&As[r][c]) =
            *reinterpret_cast<const uint4*>(&Xb[(size_t)(p0 + r) * DD + c]);
    }
    #pragma unroll
    for (int it = 0; it < 8; ++it) {
        int idx = it * 256 + tid;
        int r = idx >> 4, c = (idx & 15) * 8;
        *reinterpret_cast<uint4*>(&Bs[r][c]) =
            *reinterpret_cast<const uint4*>(&WT[(size_t)(n0 + r) * DD + c]);
    }
    __syncthreads();
    const int w = tid >> 6, lane = tid & 63;
    const int wm = w >> 1, wn = w & 1;
    const int lr = lane & 15, lg = lane >> 4;
    const f32x4 zz = {0.f, 0.f, 0.f, 0.f};
    f32x4 acc[2][4];
    #pragma unroll
    for (int m = 0; m < 2; ++m)
        #pragma unroll
        for (int n = 0; n < 4; ++n) acc[m][n] = zz;
    #pragma unroll
    for (int kk = 0; kk < 4; ++kk) {
        bf16x8 a0 = *reinterpret_cast<const bf16x8*>(&As[wm * 32 + lr][kk * 32 + lg * 8]);
        bf16x8 a1 = *reinterpret_cast<const bf16x8*>(&As[wm * 32 + 16 + lr][kk * 32 + lg * 8]);
        #pragma unroll
        for (int n = 0; n < 4; ++n) {
            bf16x8 b = *reinterpret_cast<const bf16x8*>(&Bs[wn * 64 + n * 16 + lr][kk * 32 + lg * 8]);
            acc[0][n] = mfma16(a0, b, acc[0][n]);
            acc[1][n] = mfma16(a1, b, acc[1][n]);
        }
    }
    const int seg = n0 >> 7;   // 0:q 1:k 2:v 3:g
    #pragma unroll
    for (int n = 0; n < 4; ++n) {
        const int cc = (n0 & 127) + wn * 64 + n * 16 + lr;
        const float bgv = (seg == 3) ? bg[cc] : 0.f;
        #pragma unroll
        for (int m = 0; m < 2; ++m) {
            #pragma unroll
            for (int r = 0; r < 4; ++r) {
                const int p = p0 + wm * 32 + m * 16 + lg * 4 + r;
                const float v = acc[m][n][r];
                const size_t off = (size_t)p * DD + cc;
                if (seg == 0)      Qo[off] = f2bf(v * SCALE);
                else if (seg == 1) Ko[off] = f2bf(v);
                else if (seg == 2) Vo[off] = f2bf(v);
                else Go[off] = f2bf(1.0f / (1.0f + __expf(-(v + bgv))));
            }
        }
    }
}

// ---------------- K3: attention, swapped QK^T, LDS-resident K/V ------------
// grid 1024 (= 256 i * 4 h) x 256 threads (4 waves). LDS 46.6KB -> 3 blk/CU.
__global__ __launch_bounds__(256, 3) void k_attn4(
    const ushort* __restrict__ Qw, const ushort* __restrict__ Kw,
    const ushort* __restrict__ Vw, const ushort* __restrict__ Gw,
    const ushort* __restrict__ Bo, const int* __restrict__ mask,
    ushort* __restrict__ OPre)
{
    __shared__ __align__(16) ushort Ks[256][40];   // K rows, 80B stride: 20.0KB
    __shared__ __align__(16) ushort Vt[32][264];   // V^T [d][k]: 16.9KB
    __shared__ __align__(16) ushort Pl[4][16][72]; // per-wave P, 64-key chunk: 9.2KB
    const int tid = threadIdx.x, w = tid >> 6, lane = tid & 63;
    const int lr = lane & 15, lg = lane >> 4;
    const int i = blockIdx.x >> 2, h = blockIdx.x & 3;
    const int ib = i * NP;
    const size_t base = (size_t)ib * DD + h * 32;

    // stage K rows (uint4 = 8 ushorts)
    #pragma unroll
    for (int it = 0; it < 4; ++it) {
        int idx = it * 256 + tid;
        int r = idx >> 2, c = (idx & 3) * 8;
        *reinterpret_cast<uint4*>(&Ks[r][c]) =
            *reinterpret_cast<const uint4*>(&Kw[base + (size_t)r * DD + c]);
    }
    // stage V^T
    #pragma unroll
    for (int it = 0; it < 8; ++it) {
        int idx = it * 256 + tid;
        int k = idx >> 3, dc = (idx & 7) * 4;
        ushort4 v = *reinterpret_cast<const ushort4*>(&Vw[base + (size_t)k * DD + dc]);
        Vt[dc + 0][k] = v.x; Vt[dc + 1][k] = v.y;
        Vt[dc + 2][k] = v.z; Vt[dc + 3][k] = v.w;
    }
    __syncthreads();

    const ushort* bias_h = Bo + (size_t)h * 65536;
    const f32x4 zz = {0.f, 0.f, 0.f, 0.f};

    for (int jt = 0; jt < 4; ++jt) {
        const int jb = jt * 64 + w * 16;
        const int jq = jb + lr;             // this lane's softmax row
        // Q B-frag from global (each row read once per block; 4 lanes = 64B line)
        bf16x8 q = *reinterpret_cast<const bf16x8*>(&Qw[base + (size_t)jq * DD + lg * 8]);
        // scores: accumulator initialized with bias (bf16 -> f32)
        f32x4 s[16];
        const ushort* bp = bias_h + (size_t)jq * 256 + 4 * lg;
        #pragma unroll
        for (int fn = 0; fn < 16; ++fn) {
            uint2 bb = *reinterpret_cast<const uint2*>(bp + fn * 16);
            f32x4 sv;
            sv[0] = bf2f((ushort)(bb.x & 0xffffu));
            sv[1] = bf2f((ushort)(bb.x >> 16));
            sv[2] = bf2f((ushort)(bb.y & 0xffffu));
            sv[3] = bf2f((ushort)(bb.y >> 16));
            s[fn] = sv;
        }
        #pragma unroll
        for (int fn = 0; fn < 16; ++fn) {
            bf16x8 a = *reinterpret_cast<const bf16x8*>(&Ks[fn * 16 + lr][lg * 8]);
            s[fn] = mfma16(a, q, s[fn]);    // S^T[k][j]
        }
        // softmax over k for row jq (4-lane group: xor 16, 32)
        float mx = -3.402823466e38f;
        #pragma unroll
        for (int fn = 0; fn < 16; ++fn) {
            float m01 = fmaxf(s[fn][0], s[fn][1]);
            float m23 = fmaxf(s[fn][2], s[fn][3]);
            mx = fmaxf(mx, fmaxf(m01, m23));
        }
        mx = fmaxf(mx, __shfl_xor(mx, 16));
        mx = fmaxf(mx, __shfl_xor(mx, 32));
        float sum = 0.f;
        #pragma unroll
        for (int fn = 0; fn < 16; ++fn) {
            #pragma unroll
            for (int r = 0; r < 4; ++r) {
                float e = __expf(s[fn][r] - mx);
                s[fn][r] = e; sum += e;
            }
        }
        sum += __shfl_xor(sum, 16);
        sum += __shfl_xor(sum, 32);
        const bool masked = (mask[ib + jq] == 0);
        const float inv = masked ? 1.0f : (1.0f / sum);  // normalization deferred

        // PV in 4 chunks of 64 keys; P stays wave-private (no barriers)
        f32x4 o0 = zz, o1 = zz;
        #pragma unroll
        for (int c = 0; c < 4; ++c) {
            #pragma unroll
            for (int fnl = 0; fnl < 4; ++fnl) {
                const int fn = c * 4 + fnl;
                unsigned int w0 = packbf(s[fn][0], s[fn][1]);
                unsigned int w1 = packbf(s[fn][2], s[fn][3]);
                if (masked) { w0 = 0x3B803B80u; w1 = 0x3B803B80u; }  // 1/256
                uint2 pw; pw.x = w0; pw.y = w1;
                *reinterpret_cast<uint2*>(&Pl[w][lr][fnl * 16 + 4 * lg]) = pw;
            }
            #pragma unroll
            for (int ks = 0; ks < 2; ++ks) {
                bf16x8 pa = *reinterpret_cast<const bf16x8*>(&Pl[w][lr][ks * 32 + lg * 8]);
                bf16x8 v0 = *reinterpret_cast<const bf16x8*>(&Vt[lr][c * 64 + ks * 32 + lg * 8]);
                bf16x8 v1 = *reinterpret_cast<const bf16x8*>(&Vt[16 + lr][c * 64 + ks * 32 + lg * 8]);
                o0 = mfma16(pa, v0, o0);
                o1 = mfma16(pa, v1, o1);
            }
        }
        // epilogue: rows j = jb + 4*lg + r, cols d = lr / 16+lr
        #pragma unroll
        for (int r = 0; r < 4; ++r) {
            const int j = jb + 4 * lg + r;
            const bool mk = (mask[ib + j] == 0);
            const float iv = __shfl(inv, 4 * lg + r);
            const size_t off = base + (size_t)j * DD;
            const float g0 = mk ? NEGV : bf2f(Gw[off + lr]);
            const float g1 = mk ? NEGV : bf2f(Gw[off + 16 + lr]);
            OPre[off + lr]      = f2bf(o0[r] * iv * g0);
            OPre[off + 16 + lr] = f2bf(o1[r] * iv * g1);
        }
    }
}

// ---------------- K4: out = OPre @ Wout + bout (MFMA) ----------------------
__global__ __launch_bounds__(256) void k_gemm_out(
    const ushort* __restrict__ OPre, const ushort* __restrict__ WoT,
    const float* __restrict__ bout, float* __restrict__ out)
{
    __shared__ __align__(16) ushort As[64][136];
    __shared__ __align__(16) ushort Bs[128][136];
    const int tid = threadIdx.x;
    const int p0 = blockIdx.x * 64;
    #pragma unroll
    for (int it = 0; it < 4; ++it) {
        int idx = it * 256 + tid;
        int r = idx >> 4, c = (idx & 15) * 8;
        *reinterpret_cast<uint4*>(&As[r][c]) =
            *reinterpret_cast<const uint4*>(&OPre[(size_t)(p0 + r) * DD + c]);
    }
    #pragma unroll
    for (int it = 0; it < 8; ++it) {
        int idx = it * 256 + tid;
        int r = idx >> 4, c = (idx & 15) * 8;
        *reinterpret_cast<uint4*>(&Bs[r][c]) =
            *reinterpret_cast<const uint4*>(&WoT[(size_t)r * DD + c]);
    }
    __syncthreads();
    const int w = tid >> 6, lane = tid & 63;
    const int wm = w >> 1, wn = w & 1;
    const int lr = lane & 15, lg = lane >> 4;
    const f32x4 zz = {0.f, 0.f, 0.f, 0.f};
    f32x4 acc[2][4];
    #pragma unroll
    for (int m = 0; m < 2; ++m)
        #pragma unroll
        for (int n = 0; n < 4; ++n) acc[m][n] = zz;
    #pragma unroll
    for (int kk = 0; kk < 4; ++kk) {
        bf16x8 a0 = *reinterpret_cast<const bf16x8*>(&As[wm * 32 + lr][kk * 32 + lg * 8]);
        bf16x8 a1 = *reinterpret_cast<const bf16x8*>(&As[wm * 32 + 16 + lr][kk * 32 + lg * 8]);
        #pragma unroll
        for (int n = 0; n < 4; ++n) {
            bf16x8 b = *reinterpret_cast<const bf16x8*>(&Bs[wn * 64 + n * 16 + lr][kk * 32 + lg * 8]);
            acc[0][n] = mfma16(a0, b, acc[0][n]);
            acc[1][n] = mfma16(a1, b, acc[1][n]);
        }
    }
    #pragma unroll
    for (int n = 0; n < 4; ++n) {
        const int c = wn * 64 + n * 16 + lr;
        const float bo = bout[c];
        #pragma unroll
        for (int m = 0; m < 2; ++m) {
            #pragma unroll
            for (int r = 0; r < 4; ++r) {
                const int p = p0 + wm * 32 + m * 16 + lg * 4 + r;
                out[(size_t)p * DD + c] = acc[m][n][r] + bo;
            }
        }
    }
}

extern "C" void kernel_launch(void* const* d_in, const int* in_sizes, int n_in,
                              void* d_out, int out_size, void* d_ws, size_t ws_size,
                              hipStream_t stream) {
    const float* edges = (const float*)d_in[0];
    const int*   mask  = (const int*)d_in[1];
    const float* gamma = (const float*)d_in[2];
    const float* beta  = (const float*)d_in[3];
    const float* Wqkv  = (const float*)d_in[4];
    const float* Wb    = (const float*)d_in[5];
    const float* Wg    = (const float*)d_in[6];
    const float* bg    = (const float*)d_in[7];
    const float* Wout  = (const float*)d_in[8];
    const float* bout  = (const float*)d_in[9];
    float* out = (float*)d_out;

    char* ws = (char*)d_ws;
    ushort* Xb  = (ushort*)(ws);
    ushort* Qw  = (ushort*)(ws + 1u * 16777216u);
    ushort* Kw  = (ushort*)(ws + 2u * 16777216u);
    ushort* Vw  = (ushort*)(ws + 3u * 16777216u);
    ushort* Gw  = (ushort*)(ws + 4u * 16777216u);
    ushort* Bo  = (ushort*)(ws + 5u * 16777216u);             // 512 KiB bf16
    ushort* WT  = (ushort*)(ws + 5u * 16777216u + 524288u);   // 128 KiB
    ushort* WoT = (ushort*)(ws + 5u * 16777216u + 524288u + 131072u); // 32 KiB
    ushort* OPre = Xb;   // Xb dead after k_gemm_qkvg

    k_wconv<<<dim3(320), dim3(256), 0, stream>>>(Wqkv, Wg, Wout, WT, WoT);
    k_ln<<<dim3(1024), dim3(256), 0, stream>>>(edges, gamma, beta, Wb, Xb, Bo);
    k_gemm_qkvg<<<dim3(1024, 4), dim3(256), 0, stream>>>(Xb, WT, bg, Qw, Kw, Vw, Gw);
    k_attn4<<<dim3(1024), dim3(256), 0, stream>>>(Qw, Kw, Vw, Gw, Bo, mask, OPre);
    k_gemm_out<<<dim3(1024), dim3(256), 0, stream>>>(OPre, WoT, bout, out);
}

// Round 5
// 194.051 us; speedup vs baseline: 1.1088x; 1.0631x over previous
//
#include <hip/hip_runtime.h>
#include <hip/hip_bf16.h>

// Triangle attention (starting node), b=1, n=256, d=128, H=4, DH=32.
// Round 4: XCD-aware (i,h) block remap so each XCD keeps one 128KB bias
// slice L2-resident; vectorized V^T staging (b64, 2-way); qkvg GEMM loops
// N-segments in-kernel to read the A-tile once.

#define NP  256
#define DD  128

typedef short bf16x8 __attribute__((ext_vector_type(8)));
typedef float f32x4  __attribute__((ext_vector_type(4)));

__device__ __forceinline__ float bf2f(ushort u) {
    union { unsigned int v; float f; } c; c.v = ((unsigned int)u) << 16; return c.f;
}
__device__ __forceinline__ ushort f2bf(float f) {
    union { float f; unsigned int v; } c; c.f = f;
    unsigned int x = c.v;
    return (ushort)((x + 0x7FFFu + ((x >> 16) & 1u)) >> 16);  // RNE
}
__device__ __forceinline__ unsigned int packbf(float a, float b) {
    __hip_bfloat162 t = __float22bfloat162_rn(make_float2(a, b));  // a -> low
    union { __hip_bfloat162 h; unsigned int u; } c; c.h = t; return c.u;
}
__device__ __forceinline__ f32x4 mfma16(bf16x8 a, bf16x8 b, f32x4 c) {
    return __builtin_amdgcn_mfma_f32_16x16x32_bf16(a, b, c, 0, 0, 0);
}

#define NEGV (-3.4028234663852886e38f)
#define SCALE 0.17677669529663687f

// ---------------- K0: W -> bf16, transposed (N-major, K-contiguous) --------
__global__ __launch_bounds__(256) void k_wconv(
    const float* __restrict__ Wqkv, const float* __restrict__ Wg,
    const float* __restrict__ Wout, ushort* __restrict__ WT,
    ushort* __restrict__ WoT)
{
    int idx = blockIdx.x * 256 + threadIdx.x;   // grid 320 -> 81920
    if (idx < 65536) {
        int n = idx >> 7, k = idx & 127;
        float v = (n < 384) ? Wqkv[(size_t)k * 384 + n]
                            : Wg[(size_t)k * 128 + (n - 384)];
        WT[idx] = f2bf(v);
    } else {
        int i2 = idx - 65536;
        int c = i2 >> 7, e = i2 & 127;
        WoT[i2] = f2bf(Wout[(size_t)e * 128 + c]);
    }
}

// ---------------- K1: LayerNorm -> x bf16, + bias GEMV (bf16 [h][p]) -------
__global__ __launch_bounds__(256) void k_ln(
    const float* __restrict__ edges, const float* __restrict__ gamma,
    const float* __restrict__ beta,  const float* __restrict__ Wb,
    ushort* __restrict__ Xb, ushort* __restrict__ Bo)
{
    __shared__ float xs[64][132];
    const int tid = threadIdx.x, w = tid >> 6, lane = tid & 63;
    const int p0 = blockIdx.x * 64;
    const float g0 = gamma[lane], g1 = gamma[lane + 64];
    const float b0 = beta[lane],  b1 = beta[lane + 64];
    for (int pp = 0; pp < 16; ++pp) {
        const int row = w * 16 + pp;
        const float* ep = edges + (size_t)(p0 + row) * DD;
        float e0 = ep[lane], e1 = ep[lane + 64];
        float s = e0 + e1;
        #pragma unroll
        for (int off = 1; off < 64; off <<= 1) s += __shfl_xor(s, off);
        float mu = s * 0.0078125f;
        float d0 = e0 - mu, d1 = e1 - mu;
        float ss = d0 * d0 + d1 * d1;
        #pragma unroll
        for (int off = 1; off < 64; off <<= 1) ss += __shfl_xor(ss, off);
        float rstd = rsqrtf(ss * 0.0078125f + 1e-5f);
        xs[row][lane]      = d0 * rstd * g0 + b0;
        xs[row][lane + 64] = d1 * rstd * g1 + b1;
    }
    __syncthreads();
    #pragma unroll
    for (int pass = 0; pass < 8; ++pass) {
        int idx = pass * 256 + tid;
        int r = idx >> 5, c = (idx & 31) * 4;
        ushort4 o;
        o.x = f2bf(xs[r][c + 0]); o.y = f2bf(xs[r][c + 1]);
        o.z = f2bf(xs[r][c + 2]); o.w = f2bf(xs[r][c + 3]);
        *reinterpret_cast<ushort4*>(&Xb[(size_t)(p0 + r) * DD + c]) = o;
    }
    // bias = x @ Wb, bf16, layout Bo[h][p] (p = j*256 + k)
    {
        const int r = tid >> 2, hh = tid & 3;
        float acc = 0.f;
        for (int e = 0; e < DD; ++e) acc += xs[r][e] * Wb[e * 4 + hh];
        Bo[(size_t)hh * 65536 + p0 + r] = f2bf(acc);
    }
}

// ---------------- K2: x @ [Wqkv|Wg] via MFMA; A-tile staged once -----------
// grid 1024 x 256 thr; loops the 4 N-segments in-kernel (Bs hot in L2).
__global__ __launch_bounds__(256) void k_gemm_qkvg(
    const ushort* __restrict__ Xb, const ushort* __restrict__ WT,
    const float* __restrict__ bg,
    ushort* __restrict__ Qo, ushort* __restrict__ Ko,
    ushort* __restrict__ Vo, ushort* __restrict__ Go)
{
    __shared__ __align__(16) ushort As[64][136];
    __shared__ __align__(16) ushort Bs[128][136];
    const int tid = threadIdx.x;
    const int p0 = blockIdx.x * 64;
    #pragma unroll
    for (int it = 0; it < 4; ++it) {
        int idx = it * 256 + tid;
        int r = idx >> 4, c = (idx & 15) * 8;
        *reinterpret_cast<uint4*>(&As[r][c]) =
            *reinterpret_cast<const uint4*>(&Xb[(size_t)(p0 + r) * DD + c]);
    }
    const int w = tid >> 6, lane = tid & 63;
    const int wm = w >> 1, wn = w & 1;
    const int lr = lane & 15, lg = lane >> 4;
    const f32x4 zz = {0.f, 0.f, 0.f, 0.f};

    for (int seg = 0; seg < 4; ++seg) {
        const int n0 = seg * 128;
        __syncthreads();   // prev-seg Bs reads done (and As visible on seg 0)
        #pragma unroll
        for (int it = 0; it < 8; ++it) {
            int idx = it * 256 + tid;
            int r = idx >> 4, c = (idx & 15) * 8;
            *reinterpret_cast<uint4*>(&Bs[r][c]) =
                *reinterpret_cast<const uint4*>(&WT[(size_t)(n0 + r) * DD + c]);
        }
        __syncthreads();
        f32x4 acc[2][4];
        #pragma unroll
        for (int m = 0; m < 2; ++m)
            #pragma unroll
            for (int n = 0; n < 4; ++n) acc[m][n] = zz;
        #pragma unroll
        for (int kk = 0; kk < 4; ++kk) {
            bf16x8 a0 = *reinterpret_cast<const bf16x8*>(&As[wm * 32 + lr][kk * 32 + lg * 8]);
            bf16x8 a1 = *reinterpret_cast<const bf16x8*>(&As[wm * 32 + 16 + lr][kk * 32 + lg * 8]);
            #pragma unroll
            for (int n = 0; n < 4; ++n) {
                bf16x8 b = *reinterpret_cast<const bf16x8*>(&Bs[wn * 64 + n * 16 + lr][kk * 32 + lg * 8]);
                acc[0][n] = mfma16(a0, b, acc[0][n]);
                acc[1][n] = mfma16(a1, b, acc[1][n]);
            }
        }
        #pragma unroll
        for (int n = 0; n < 4; ++n) {
            const int cc = wn * 64 + n * 16 + lr;
            const float bgv = (seg == 3) ? bg[cc] : 0.f;
            #pragma unroll
            for (int m = 0; m < 2; ++m) {
                #pragma unroll
                for (int r = 0; r < 4; ++r) {
                    const int p = p0 + wm * 32 + m * 16 + lg * 4 + r;
                    const float v = acc[m][n][r];
                    const size_t off = (size_t)p * DD + cc;
                    if (seg == 0)      Qo[off] = f2bf(v * SCALE);
                    else if (seg == 1) Ko[off] = f2bf(v);
                    else if (seg == 2) Vo[off] = f2bf(v);
                    else Go[off] = f2bf(1.0f / (1.0f + __expf(-(v + bgv))));
                }
            }
        }
    }
}

// ---------------- K3: attention, swapped QK^T, XCD-grouped by head ---------
// grid 1024 x 256 threads (4 waves). LDS ~46.7KB -> 3 blk/CU.
// Block remap: h = (bid&7)>>1, i = (bid>>3)*2 + (bid&1)  (bijective).
// With round-robin XCD dispatch each XCD sees ONE head -> its 128KB bias
// slice stays L2-resident.
__global__ __launch_bounds__(256, 3) void k_attn5(
    const ushort* __restrict__ Qw, const ushort* __restrict__ Kw,
    const ushort* __restrict__ Vw, const ushort* __restrict__ Gw,
    const ushort* __restrict__ Bo, const int* __restrict__ mask,
    ushort* __restrict__ OPre)
{
    __shared__ __align__(16) ushort Ks[256][40];   // K rows, 80B stride: 20.0KB
    __shared__ __align__(16) ushort Vt[32][268];   // V^T [d][k], 536B stride: 16.75KB
    __shared__ __align__(16) ushort Pl[4][16][72]; // per-wave P, 64-key chunk: 9.2KB
    const int tid = threadIdx.x, w = tid >> 6, lane = tid & 63;
    const int lr = lane & 15, lg = lane >> 4;
    const int bid = blockIdx.x;
    const int h = (bid & 7) >> 1;
    const int i = ((bid >> 3) << 1) | (bid & 1);
    const int ib = i * NP;
    const size_t base = (size_t)ib * DD + h * 32;

    // stage K rows (uint4 = 8 ushorts)
    #pragma unroll
    for (int it = 0; it < 4; ++it) {
        int idx = it * 256 + tid;
        int r = idx >> 2, c = (idx & 3) * 8;
        *reinterpret_cast<uint4*>(&Ks[r][c]) =
            *reinterpret_cast<const uint4*>(&Kw[base + (size_t)r * DD + c]);
    }
    // stage V^T: lane owns (d, k quad); coalesced 2B reads, b64 LDS write
    #pragma unroll
    for (int it = 0; it < 8; ++it) {
        int idx = it * 256 + tid;
        int d = idx & 31, k4 = (idx >> 5) * 4;
        ushort4 v;
        v.x = Vw[base + (size_t)(k4 + 0) * DD + d];
        v.y = Vw[base + (size_t)(k4 + 1) * DD + d];
        v.z = Vw[base + (size_t)(k4 + 2) * DD + d];
        v.w = Vw[base + (size_t)(k4 + 3) * DD + d];
        *reinterpret_cast<ushort4*>(&Vt[d][k4]) = v;
    }
    __syncthreads();

    const ushort* bias_h = Bo + (size_t)h * 65536;
    const f32x4 zz = {0.f, 0.f, 0.f, 0.f};

    for (int jt = 0; jt < 4; ++jt) {
        const int jb = jt * 64 + w * 16;
        const int jq = jb + lr;             // this lane's softmax row
        bf16x8 q = *reinterpret_cast<const bf16x8*>(&Qw[base + (size_t)jq * DD + lg * 8]);
        // scores: accumulator initialized with bias (bf16 -> f32)
        f32x4 s[16];
        const ushort* bp = bias_h + (size_t)jq * 256 + 4 * lg;
        #pragma unroll
        for (int fn = 0; fn < 16; ++fn) {
            uint2 bb = *reinterpret_cast<const uint2*>(bp + fn * 16);
            f32x4 sv;
            sv[0] = bf2f((ushort)(bb.x & 0xffffu));
            sv[1] = bf2f((ushort)(bb.x >> 16));
            sv[2] = bf2f((ushort)(bb.y & 0xffffu));
            sv[3] = bf2f((ushort)(bb.y >> 16));
            s[fn] = sv;
        }
        #pragma unroll
        for (int fn = 0; fn < 16; ++fn) {
            bf16x8 a = *reinterpret_cast<const bf16x8*>(&Ks[fn * 16 + lr][lg * 8]);
            s[fn] = mfma16(a, q, s[fn]);    // S^T[k][j]
        }
        // softmax over k for row jq (4-lane group: xor 16, 32)
        float mx = -3.402823466e38f;
        #pragma unroll
        for (int fn = 0; fn < 16; ++fn) {
            float m01 = fmaxf(s[fn][0], s[fn][1]);
            float m23 = fmaxf(s[fn][2], s[fn][3]);
            mx = fmaxf(mx, fmaxf(m01, m23));
        }
        mx = fmaxf(mx, __shfl_xor(mx, 16));
        mx = fmaxf(mx, __shfl_xor(mx, 32));
        float sum = 0.f;
        #pragma unroll
        for (int fn = 0; fn < 16; ++fn) {
            #pragma unroll
            for (int r = 0; r < 4; ++r) {
                float e = __expf(s[fn][r] - mx);
                s[fn][r] = e; sum += e;
            }
        }
        sum += __shfl_xor(sum, 16);
        sum += __shfl_xor(sum, 32);
        const bool masked = (mask[ib + jq] == 0);
        const float inv = masked ? 1.0f : (1.0f / sum);  // normalization deferred

        // PV in 4 chunks of 64 keys; P stays wave-private (no barriers)
        f32x4 o0 = zz, o1 = zz;
        #pragma unroll
        for (int c = 0; c < 4; ++c) {
            #pragma unroll
            for (int fnl = 0; fnl < 4; ++fnl) {
                const int fn = c * 4 + fnl;
                unsigned int w0 = packbf(s[fn][0], s[fn][1]);
                unsigned int w1 = packbf(s[fn][2], s[fn][3]);
                if (masked) { w0 = 0x3B803B80u; w1 = 0x3B803B80u; }  // 1/256
                uint2 pw; pw.x = w0; pw.y = w1;
                *reinterpret_cast<uint2*>(&Pl[w][lr][fnl * 16 + 4 * lg]) = pw;
            }
            #pragma unroll
            for (int ks = 0; ks < 2; ++ks) {
                bf16x8 pa = *reinterpret_cast<const bf16x8*>(&Pl[w][lr][ks * 32 + lg * 8]);
                bf16x8 v0 = *reinterpret_cast<const bf16x8*>(&Vt[lr][c * 64 + ks * 32 + lg * 8]);
                bf16x8 v1 = *reinterpret_cast<const bf16x8*>(&Vt[16 + lr][c * 64 + ks * 32 + lg * 8]);
                o0 = mfma16(pa, v0, o0);
                o1 = mfma16(pa, v1, o1);
            }
        }
        // epilogue: rows j = jb + 4*lg + r, cols d = lr / 16+lr
        #pragma unroll
        for (int r = 0; r < 4; ++r) {
            const int j = jb + 4 * lg + r;
            const bool mk = (mask[ib + j] == 0);
            const float iv = __shfl(inv, 4 * lg + r);
            const size_t off = base + (size_t)j * DD;
            const float g0 = mk ? NEGV : bf2f(Gw[off + lr]);
            const float g1 = mk ? NEGV : bf2f(Gw[off + 16 + lr]);
            OPre[off + lr]      = f2bf(o0[r] * iv * g0);
            OPre[off + 16 + lr] = f2bf(o1[r] * iv * g1);
        }
    }
}

// ---------------- K4: out = OPre @ Wout + bout (MFMA) ----------------------
__global__ __launch_bounds__(256) void k_gemm_out(
    const ushort* __restrict__ OPre, const ushort* __restrict__ WoT,
    const float* __restrict__ bout, float* __restrict__ out)
{
    __shared__ __align__(16) ushort As[64][136];
    __shared__ __align__(16) ushort Bs[128][136];
    const int tid = threadIdx.x;
    const int p0 = blockIdx.x * 64;
    #pragma unroll
    for (int it = 0; it < 4; ++it) {
        int idx = it * 256 + tid;
        int r = idx >> 4, c = (idx & 15) * 8;
        *reinterpret_cast<uint4*>(&As[r][c]) =
            *reinterpret_cast<const uint4*>(&OPre[(size_t)(p0 + r) * DD + c]);
    }
    #pragma unroll
    for (int it = 0; it < 8; ++it) {
        int idx = it * 256 + tid;
        int r = idx >> 4, c = (idx & 15) * 8;
        *reinterpret_cast<uint4*>(&Bs[r][c]) =
            *reinterpret_cast<const uint4*>(&WoT[(size_t)r * DD + c]);
    }
    __syncthreads();
    const int w = tid >> 6, lane = tid & 63;
    const int wm = w >> 1, wn = w & 1;
    const int lr = lane & 15, lg = lane >> 4;
    const f32x4 zz = {0.f, 0.f, 0.f, 0.f};
    f32x4 acc[2][4];
    #pragma unroll
    for (int m = 0; m < 2; ++m)
        #pragma unroll
        for (int n = 0; n < 4; ++n) acc[m][n] = zz;
    #pragma unroll
    for (int kk = 0; kk < 4; ++kk) {
        bf16x8 a0 = *reinterpret_cast<const bf16x8*>(&As[wm * 32 + lr][kk * 32 + lg * 8]);
        bf16x8 a1 = *reinterpret_cast<const bf16x8*>(&As[wm * 32 + 16 + lr][kk * 32 + lg * 8]);
        #pragma unroll
        for (int n = 0; n < 4; ++n) {
            bf16x8 b = *reinterpret_cast<const bf16x8*>(&Bs[wn * 64 + n * 16 + lr][kk * 32 + lg * 8]);
            acc[0][n] = mfma16(a0, b, acc[0][n]);
            acc[1][n] = mfma16(a1, b, acc[1][n]);
        }
    }
    #pragma unroll
    for (int n = 0; n < 4; ++n) {
        const int c = wn * 64 + n * 16 + lr;
        const float bo = bout[c];
        #pragma unroll
        for (int m = 0; m < 2; ++m) {
            #pragma unroll
            for (int r = 0; r < 4; ++r) {
                const int p = p0 + wm * 32 + m * 16 + lg * 4 + r;
                out[(size_t)p * DD + c] = acc[m][n][r] + bo;
            }
        }
    }
}

extern "C" void kernel_launch(void* const* d_in, const int* in_sizes, int n_in,
                              void* d_out, int out_size, void* d_ws, size_t ws_size,
                              hipStream_t stream) {
    const float* edges = (const float*)d_in[0];
    const int*   mask  = (const int*)d_in[1];
    const float* gamma = (const float*)d_in[2];
    const float* beta  = (const float*)d_in[3];
    const float* Wqkv  = (const float*)d_in[4];
    const float* Wb    = (const float*)d_in[5];
    const float* Wg    = (const float*)d_in[6];
    const float* bg    = (const float*)d_in[7];
    const float* Wout  = (const float*)d_in[8];
    const float* bout  = (const float*)d_in[9];
    float* out = (float*)d_out;

    char* ws = (char*)d_ws;
    ushort* Xb  = (ushort*)(ws);
    ushort* Qw  = (ushort*)(ws + 1u * 16777216u);
    ushort* Kw  = (ushort*)(ws + 2u * 16777216u);
    ushort* Vw  = (ushort*)(ws + 3u * 16777216u);
    ushort* Gw  = (ushort*)(ws + 4u * 16777216u);
    ushort* Bo  = (ushort*)(ws + 5u * 16777216u);             // 512 KiB bf16
    ushort* WT  = (ushort*)(ws + 5u * 16777216u + 524288u);   // 128 KiB
    ushort* WoT = (ushort*)(ws + 5u * 16777216u + 524288u + 131072u); // 32 KiB
    ushort* OPre = Xb;   // Xb dead after k_gemm_qkvg

    k_wconv<<<dim3(320), dim3(256), 0, stream>>>(Wqkv, Wg, Wout, WT, WoT);
    k_ln<<<dim3(1024), dim3(256), 0, stream>>>(edges, gamma, beta, Wb, Xb, Bo);
    k_gemm_qkvg<<<dim3(1024), dim3(256), 0, stream>>>(Xb, WT, bg, Qw, Kw, Vw, Gw);
    k_attn5<<<dim3(1024), dim3(256), 0, stream>>>(Qw, Kw, Vw, Gw, Bo, mask, OPre);
    k_gemm_out<<<dim3(1024), dim3(256), 0, stream>>>(OPre, WoT, bout, out);
}

// Round 7
// 188.481 us; speedup vs baseline: 1.1415x; 1.0296x over previous
//
#include <hip/hip_runtime.h>
#include <hip/hip_bf16.h>
#include <hip/hip_fp16.h>

// Triangle attention (starting node), b=1, n=256, d=128, H=4, DH=32.
// Round 6: round-5 design (head-blocked layouts [h][i][k][32] for
// Q/K/V/G/OPre, fp8 e5m2 bias) + compile fix (hip_fp16.h) + staging cleanup.

#define NP  256
#define DD  128
#define HSTR 2097152   // 65536*32, per-head block stride (elements)

typedef short bf16x8 __attribute__((ext_vector_type(8)));
typedef float f32x4  __attribute__((ext_vector_type(4)));

__device__ __forceinline__ float bf2f(ushort u) {
    union { unsigned int v; float f; } c; c.v = ((unsigned int)u) << 16; return c.f;
}
__device__ __forceinline__ ushort f2bf(float f) {
    union { float f; unsigned int v; } c; c.f = f;
    unsigned int x = c.v;
    return (ushort)((x + 0x7FFFu + ((x >> 16) & 1u)) >> 16);  // RNE
}
__device__ __forceinline__ unsigned int packbf(float a, float b) {
    __hip_bfloat162 t = __float22bfloat162_rn(make_float2(a, b));  // a -> low
    union { __hip_bfloat162 h; unsigned int u; } c; c.h = t; return c.u;
}
__device__ __forceinline__ f32x4 mfma16(bf16x8 a, bf16x8 b, f32x4 c) {
    return __builtin_amdgcn_mfma_f32_16x16x32_bf16(a, b, c, 0, 0, 0);
}
// fp8 e5m2 (top byte of fp16), RNE
__device__ __forceinline__ unsigned char f2e5m2(float f) {
    __half h = __float2half(f);
    ushort hb = __half_as_ushort(h);
    unsigned int u = (unsigned int)hb + 0x7Fu + ((hb >> 8) & 1u);
    return (unsigned char)(u >> 8);
}
__device__ __forceinline__ float e5m2f(unsigned int b) {
    return __half2float(__ushort_as_half((ushort)(b << 8)));
}

#define NEGV (-3.4028234663852886e38f)
#define SCALE 0.17677669529663687f

// ---------------- K0: W -> bf16, transposed (N-major, K-contiguous) --------
__global__ __launch_bounds__(256) void k_wconv(
    const float* __restrict__ Wqkv, const float* __restrict__ Wg,
    const float* __restrict__ Wout, ushort* __restrict__ WT,
    ushort* __restrict__ WoT)
{
    int idx = blockIdx.x * 256 + threadIdx.x;   // grid 320 -> 81920
    if (idx < 65536) {
        int n = idx >> 7, k = idx & 127;
        float v = (n < 384) ? Wqkv[(size_t)k * 384 + n]
                            : Wg[(size_t)k * 128 + (n - 384)];
        WT[idx] = f2bf(v);
    } else {
        int i2 = idx - 65536;
        int c = i2 >> 7, e = i2 & 127;
        WoT[i2] = f2bf(Wout[(size_t)e * 128 + c]);
    }
}

// ---------------- K1: LayerNorm -> x bf16, + bias GEMV (fp8 [h][p]) --------
__global__ __launch_bounds__(256) void k_ln(
    const float* __restrict__ edges, const float* __restrict__ gamma,
    const float* __restrict__ beta,  const float* __restrict__ Wb,
    ushort* __restrict__ Xb, unsigned char* __restrict__ Bo8)
{
    __shared__ float xs[64][132];
    const int tid = threadIdx.x, w = tid >> 6, lane = tid & 63;
    const int p0 = blockIdx.x * 64;
    const float g0 = gamma[lane], g1 = gamma[lane + 64];
    const float b0 = beta[lane],  b1 = beta[lane + 64];
    for (int pp = 0; pp < 16; ++pp) {
        const int row = w * 16 + pp;
        const float* ep = edges + (size_t)(p0 + row) * DD;
        float e0 = ep[lane], e1 = ep[lane + 64];
        float s = e0 + e1;
        #pragma unroll
        for (int off = 1; off < 64; off <<= 1) s += __shfl_xor(s, off);
        float mu = s * 0.0078125f;
        float d0 = e0 - mu, d1 = e1 - mu;
        float ss = d0 * d0 + d1 * d1;
        #pragma unroll
        for (int off = 1; off < 64; off <<= 1) ss += __shfl_xor(ss, off);
        float rstd = rsqrtf(ss * 0.0078125f + 1e-5f);
        xs[row][lane]      = d0 * rstd * g0 + b0;
        xs[row][lane + 64] = d1 * rstd * g1 + b1;
    }
    __syncthreads();
    #pragma unroll
    for (int pass = 0; pass < 8; ++pass) {
        int idx = pass * 256 + tid;
        int r = idx >> 5, c = (idx & 31) * 4;
        ushort4 o;
        o.x = f2bf(xs[r][c + 0]); o.y = f2bf(xs[r][c + 1]);
        o.z = f2bf(xs[r][c + 2]); o.w = f2bf(xs[r][c + 3]);
        *reinterpret_cast<ushort4*>(&Xb[(size_t)(p0 + r) * DD + c]) = o;
    }
    // bias = x @ Wb, fp8 e5m2, layout Bo8[h][p] (p = j*256 + k)
    {
        const int r = tid >> 2, hh = tid & 3;
        float acc = 0.f;
        for (int e = 0; e < DD; ++e) acc += xs[r][e] * Wb[e * 4 + hh];
        Bo8[(size_t)hh * 65536 + p0 + r] = f2e5m2(acc);
    }
}

// ---------------- K2: x @ [Wqkv|Wg] via MFMA; head-blocked outputs ---------
// grid 1024 x 256 thr; loops the 4 N-segments in-kernel.
__global__ __launch_bounds__(256) void k_gemm_qkvg(
    const ushort* __restrict__ Xb, const ushort* __restrict__ WT,
    const float* __restrict__ bg,
    ushort* __restrict__ Qo, ushort* __restrict__ Ko,
    ushort* __restrict__ Vo, ushort* __restrict__ Go)
{
    __shared__ __align__(16) ushort As[64][136];
    __shared__ __align__(16) ushort Bs[128][136];
    const int tid = threadIdx.x;
    const int p0 = blockIdx.x * 64;
    #pragma unroll
    for (int it = 0; it < 4; ++it) {
        int idx = it * 256 + tid;
        int r = idx >> 4, c = (idx & 15) * 8;
        *reinterpret_cast<uint4*>(&As[r][c]) =
            *reinterpret_cast<const uint4*>(&Xb[(size_t)(p0 + r) * DD + c]);
    }
    const int w = tid >> 6, lane = tid & 63;
    const int wm = w >> 1, wn = w & 1;
    const int lr = lane & 15, lg = lane >> 4;
    const f32x4 zz = {0.f, 0.f, 0.f, 0.f};

    for (int seg = 0; seg < 4; ++seg) {
        const int n0 = seg * 128;
        __syncthreads();   // prev-seg Bs reads done (and As visible on seg 0)
        #pragma unroll
        for (int it = 0; it < 8; ++it) {
            int idx = it * 256 + tid;
            int r = idx >> 4, c = (idx & 15) * 8;
            *reinterpret_cast<uint4*>(&Bs[r][c]) =
                *reinterpret_cast<const uint4*>(&WT[(size_t)(n0 + r) * DD + c]);
        }
        __syncthreads();
        f32x4 acc[2][4];
        #pragma unroll
        for (int m = 0; m < 2; ++m)
            #pragma unroll
            for (int n = 0; n < 4; ++n) acc[m][n] = zz;
        #pragma unroll
        for (int kk = 0; kk < 4; ++kk) {
            bf16x8 a0 = *reinterpret_cast<const bf16x8*>(&As[wm * 32 + lr][kk * 32 + lg * 8]);
            bf16x8 a1 = *reinterpret_cast<const bf16x8*>(&As[wm * 32 + 16 + lr][kk * 32 + lg * 8]);
            #pragma unroll
            for (int n = 0; n < 4; ++n) {
                bf16x8 b = *reinterpret_cast<const bf16x8*>(&Bs[wn * 64 + n * 16 + lr][kk * 32 + lg * 8]);
                acc[0][n] = mfma16(a0, b, acc[0][n]);
                acc[1][n] = mfma16(a1, b, acc[1][n]);
            }
        }
        #pragma unroll
        for (int n = 0; n < 4; ++n) {
            const int cc = wn * 64 + n * 16 + lr;
            const int hh = cc >> 5, dh = cc & 31;
            const float bgv = (seg == 3) ? bg[cc] : 0.f;
            #pragma unroll
            for (int m = 0; m < 2; ++m) {
                #pragma unroll
                for (int r = 0; r < 4; ++r) {
                    const int p = p0 + wm * 32 + m * 16 + lg * 4 + r;
                    const float v = acc[m][n][r];
                    const size_t off = (size_t)hh * HSTR + (size_t)p * 32 + dh;
                    if (seg == 0)      Qo[off] = f2bf(v * SCALE);
                    else if (seg == 1) Ko[off] = f2bf(v);
                    else if (seg == 2) Vo[off] = f2bf(v);
                    else Go[off] = f2bf(1.0f / (1.0f + __expf(-(v + bgv))));
                }
            }
        }
    }
}

// ---------------- K3: attention, head-blocked I/O, XCD-grouped by head -----
// grid 1024 x 256 threads (4 waves). LDS ~46.8KB -> 3 blk/CU.
__global__ __launch_bounds__(256, 3) void k_attn6(
    const ushort* __restrict__ Qw, const ushort* __restrict__ Kw,
    const ushort* __restrict__ Vw, const ushort* __restrict__ Gw,
    const unsigned char* __restrict__ Bo8, const int* __restrict__ mask,
    ushort* __restrict__ OPre)
{
    __shared__ __align__(16) ushort Ks[256][40];   // K rows, 80B stride: 20.0KB
    __shared__ __align__(16) ushort Vt[32][268];   // V^T [d][k]: 16.75KB
    __shared__ __align__(16) ushort Pl[4][16][72]; // per-wave P, 64-key chunk: 9.2KB
    const int tid = threadIdx.x, w = tid >> 6, lane = tid & 63;
    const int lr = lane & 15, lg = lane >> 4;
    const int bid = blockIdx.x;
    const int h = (bid & 7) >> 1;
    const int i = ((bid >> 3) << 1) | (bid & 1);
    const int ib = i * NP;
    const size_t base = (size_t)h * HSTR + (size_t)ib * 32;   // + k*32 + dh

    // stage K rows: contiguous 16KB source (uint4 = 8 ushorts)
    #pragma unroll
    for (int it = 0; it < 4; ++it) {
        int idx = it * 256 + tid;
        int r = idx >> 2, c = (idx & 3) * 8;
        *reinterpret_cast<uint4*>(&Ks[r][c]) =
            *reinterpret_cast<const uint4*>(&Kw[base + (size_t)r * 32 + c]);
    }
    // stage V^T: rows are contiguous 64B; lane-transpose into Vt
    #pragma unroll
    for (int it = 0; it < 8; ++it) {
        int idx = it * 256 + tid;
        int d = idx & 31, k4 = (idx >> 5) * 4;
        ushort4 v;
        v.x = Vw[base + (size_t)(k4 + 0) * 32 + d];
        v.y = Vw[base + (size_t)(k4 + 1) * 32 + d];
        v.z = Vw[base + (size_t)(k4 + 2) * 32 + d];
        v.w = Vw[base + (size_t)(k4 + 3) * 32 + d];
        *reinterpret_cast<ushort4*>(&Vt[d][k4]) = v;
    }
    __syncthreads();

    const unsigned char* bias_h = Bo8 + (size_t)h * 65536;
    const f32x4 zz = {0.f, 0.f, 0.f, 0.f};

    for (int jt = 0; jt < 4; ++jt) {
        const int jb = jt * 64 + w * 16;
        const int jq = jb + lr;             // this lane's softmax row
        bf16x8 q = *reinterpret_cast<const bf16x8*>(&Qw[base + (size_t)jq * 32 + lg * 8]);
        // scores: accumulator initialized with bias (fp8 e5m2 -> f32)
        f32x4 s[16];
        const unsigned char* bp = bias_h + (size_t)jq * 256 + 4 * lg;
        #pragma unroll
        for (int fn = 0; fn < 16; ++fn) {
            unsigned int bb = *reinterpret_cast<const unsigned int*>(bp + fn * 16);
            f32x4 sv;
            sv[0] = e5m2f(bb & 0xffu);
            sv[1] = e5m2f((bb >> 8) & 0xffu);
            sv[2] = e5m2f((bb >> 16) & 0xffu);
            sv[3] = e5m2f(bb >> 24);
            s[fn] = sv;
        }
        #pragma unroll
        for (int fn = 0; fn < 16; ++fn) {
            bf16x8 a = *reinterpret_cast<const bf16x8*>(&Ks[fn * 16 + lr][lg * 8]);
            s[fn] = mfma16(a, q, s[fn]);    // S^T[k][j]
        }
        // softmax over k for row jq (4-lane group: xor 16, 32)
        float mx = -3.402823466e38f;
        #pragma unroll
        for (int fn = 0; fn < 16; ++fn) {
            float m01 = fmaxf(s[fn][0], s[fn][1]);
            float m23 = fmaxf(s[fn][2], s[fn][3]);
            mx = fmaxf(mx, fmaxf(m01, m23));
        }
        mx = fmaxf(mx, __shfl_xor(mx, 16));
        mx = fmaxf(mx, __shfl_xor(mx, 32));
        float sum = 0.f;
        #pragma unroll
        for (int fn = 0; fn < 16; ++fn) {
            #pragma unroll
            for (int r = 0; r < 4; ++r) {
                float e = __expf(s[fn][r] - mx);
                s[fn][r] = e; sum += e;
            }
        }
        sum += __shfl_xor(sum, 16);
        sum += __shfl_xor(sum, 32);
        const bool masked = (mask[ib + jq] == 0);
        const float inv = masked ? 1.0f : (1.0f / sum);  // normalization deferred

        // PV in 4 chunks of 64 keys; P stays wave-private (no barriers)
        f32x4 o0 = zz, o1 = zz;
        #pragma unroll
        for (int c = 0; c < 4; ++c) {
            #pragma unroll
            for (int fnl = 0; fnl < 4; ++fnl) {
                const int fn = c * 4 + fnl;
                unsigned int w0 = packbf(s[fn][0], s[fn][1]);
                unsigned int w1 = packbf(s[fn][2], s[fn][3]);
                if (masked) { w0 = 0x3B803B80u; w1 = 0x3B803B80u; }  // 1/256
                uint2 pw; pw.x = w0; pw.y = w1;
                *reinterpret_cast<uint2*>(&Pl[w][lr][fnl * 16 + 4 * lg]) = pw;
            }
            #pragma unroll
            for (int ks = 0; ks < 2; ++ks) {
                bf16x8 pa = *reinterpret_cast<const bf16x8*>(&Pl[w][lr][ks * 32 + lg * 8]);
                bf16x8 v0 = *reinterpret_cast<const bf16x8*>(&Vt[lr][c * 64 + ks * 32 + lg * 8]);
                bf16x8 v1 = *reinterpret_cast<const bf16x8*>(&Vt[16 + lr][c * 64 + ks * 32 + lg * 8]);
                o0 = mfma16(pa, v0, o0);
                o1 = mfma16(pa, v1, o1);
            }
        }
        // epilogue: rows j = jb + 4*lg + r; head-blocked 64B-contiguous rows
        #pragma unroll
        for (int r = 0; r < 4; ++r) {
            const int j = jb + 4 * lg + r;
            const bool mk = (mask[ib + j] == 0);
            const float iv = __shfl(inv, 4 * lg + r);
            const size_t off = base + (size_t)j * 32;
            const float g0 = mk ? NEGV : bf2f(Gw[off + lr]);
            const float g1 = mk ? NEGV : bf2f(Gw[off + 16 + lr]);
            OPre[off + lr]      = f2bf(o0[r] * iv * g0);
            OPre[off + 16 + lr] = f2bf(o1[r] * iv * g1);
        }
    }
}

// ---------------- K4: out = OPre @ Wout + bout (MFMA, gathers head blocks) -
__global__ __launch_bounds__(256) void k_gemm_out(
    const ushort* __restrict__ OPre, const ushort* __restrict__ WoT,
    const float* __restrict__ bout, float* __restrict__ out)
{
    __shared__ __align__(16) ushort As[64][136];
    __shared__ __align__(16) ushort Bs[128][136];
    const int tid = threadIdx.x;
    const int p0 = blockIdx.x * 64;
    #pragma unroll
    for (int it = 0; it < 4; ++it) {
        int idx = it * 256 + tid;
        int r = idx >> 4, c = (idx & 15) * 8;
        int hh = c >> 5, dq = c & 31;
        *reinterpret_cast<uint4*>(&As[r][c]) =
            *reinterpret_cast<const uint4*>(&OPre[(size_t)hh * HSTR + (size_t)(p0 + r) * 32 + dq]);
    }
    #pragma unroll
    for (int it = 0; it < 8; ++it) {
        int idx = it * 256 + tid;
        int r = idx >> 4, c = (idx & 15) * 8;
        *reinterpret_cast<uint4*>(&Bs[r][c]) =
            *reinterpret_cast<const uint4*>(&WoT[(size_t)r * DD + c]);
    }
    __syncthreads();
    const int w = tid >> 6, lane = tid & 63;
    const int wm = w >> 1, wn = w & 1;
    const int lr = lane & 15, lg = lane >> 4;
    const f32x4 zz = {0.f, 0.f, 0.f, 0.f};
    f32x4 acc[2][4];
    #pragma unroll
    for (int m = 0; m < 2; ++m)
        #pragma unroll
        for (int n = 0; n < 4; ++n) acc[m][n] = zz;
    #pragma unroll
    for (int kk = 0; kk < 4; ++kk) {
        bf16x8 a0 = *reinterpret_cast<const bf16x8*>(&As[wm * 32 + lr][kk * 32 + lg * 8]);
        bf16x8 a1 = *reinterpret_cast<const bf16x8*>(&As[wm * 32 + 16 + lr][kk * 32 + lg * 8]);
        #pragma unroll
        for (int n = 0; n < 4; ++n) {
            bf16x8 b = *reinterpret_cast<const bf16x8*>(&Bs[wn * 64 + n * 16 + lr][kk * 32 + lg * 8]);
            acc[0][n] = mfma16(a0, b, acc[0][n]);
            acc[1][n] = mfma16(a1, b, acc[1][n]);
        }
    }
    #pragma unroll
    for (int n = 0; n < 4; ++n) {
        const int c = wn * 64 + n * 16 + lr;
        const float bo = bout[c];
        #pragma unroll
        for (int m = 0; m < 2; ++m) {
            #pragma unroll
            for (int r = 0; r < 4; ++r) {
                const int p = p0 + wm * 32 + m * 16 + lg * 4 + r;
                out[(size_t)p * DD + c] = acc[m][n][r] + bo;
            }
        }
    }
}

extern "C" void kernel_launch(void* const* d_in, const int* in_sizes, int n_in,
                              void* d_out, int out_size, void* d_ws, size_t ws_size,
                              hipStream_t stream) {
    const float* edges = (const float*)d_in[0];
    const int*   mask  = (const int*)d_in[1];
    const float* gamma = (const float*)d_in[2];
    const float* beta  = (const float*)d_in[3];
    const float* Wqkv  = (const float*)d_in[4];
    const float* Wb    = (const float*)d_in[5];
    const float* Wg    = (const float*)d_in[6];
    const float* bg    = (const float*)d_in[7];
    const float* Wout  = (const float*)d_in[8];
    const float* bout  = (const float*)d_in[9];
    float* out = (float*)d_out;

    char* ws = (char*)d_ws;
    ushort* Xb  = (ushort*)(ws);                               // 16 MiB
    ushort* Qw  = (ushort*)(ws + 1u * 16777216u);              // 16 MiB (head-blocked)
    ushort* Kw  = (ushort*)(ws + 2u * 16777216u);
    ushort* Vw  = (ushort*)(ws + 3u * 16777216u);
    ushort* Gw  = (ushort*)(ws + 4u * 16777216u);
    unsigned char* Bo8 = (unsigned char*)(ws + 5u * 16777216u);        // 256 KiB fp8
    ushort* WT  = (ushort*)(ws + 5u * 16777216u + 262144u);            // 128 KiB
    ushort* WoT = (ushort*)(ws + 5u * 16777216u + 262144u + 131072u);  // 32 KiB
    ushort* OPre = Xb;   // Xb dead after k_gemm_qkvg; OPre is head-blocked

    k_wconv<<<dim3(320), dim3(256), 0, stream>>>(Wqkv, Wg, Wout, WT, WoT);
    k_ln<<<dim3(1024), dim3(256), 0, stream>>>(edges, gamma, beta, Wb, Xb, Bo8);
    k_gemm_qkvg<<<dim3(1024), dim3(256), 0, stream>>>(Xb, WT, bg, Qw, Kw, Vw, Gw);
    k_attn6<<<dim3(1024), dim3(256), 0, stream>>>(Qw, Kw, Vw, Gw, Bo8, mask, OPre);
    k_gemm_out<<<dim3(1024), dim3(256), 0, stream>>>(OPre, WoT, bout, out);
}

// Round 8
// 117.301 us; speedup vs baseline: 1.8342x; 1.6068x over previous
//
#include <hip/hip_runtime.h>
#include <hip/hip_bf16.h>
#include <hip/hip_fp16.h>

// Triangle attention (starting node), b=1, n=256, d=128, H=4, DH=32.
// Round 7: fragment-ordered fp8 bias (4x dwordx4/lane), swapped PV so lane
// owns its softmax row (dwordx2 full-line O stores, no shuffles), gating
// moved to out-GEMM staging, grid 512 with 2 i-units/block (no tail).

#define NP  256
#define DD  128
#define HSTR 2097152   // 65536*32, per-head block stride (elements)

typedef short bf16x8 __attribute__((ext_vector_type(8)));
typedef float f32x4  __attribute__((ext_vector_type(4)));

__device__ __forceinline__ float bf2f(ushort u) {
    union { unsigned int v; float f; } c; c.v = ((unsigned int)u) << 16; return c.f;
}
__device__ __forceinline__ ushort f2bf(float f) {
    union { float f; unsigned int v; } c; c.f = f;
    unsigned int x = c.v;
    return (ushort)((x + 0x7FFFu + ((x >> 16) & 1u)) >> 16);  // RNE
}
__device__ __forceinline__ unsigned int packbf(float a, float b) {
    __hip_bfloat162 t = __float22bfloat162_rn(make_float2(a, b));  // a -> low
    union { __hip_bfloat162 h; unsigned int u; } c; c.h = t; return c.u;
}
__device__ __forceinline__ f32x4 mfma16(bf16x8 a, bf16x8 b, f32x4 c) {
    return __builtin_amdgcn_mfma_f32_16x16x32_bf16(a, b, c, 0, 0, 0);
}
// fp8 e5m2 (top byte of fp16), RNE
__device__ __forceinline__ unsigned char f2e5m2(float f) {
    __half h = __float2half(f);
    ushort hb = __half_as_ushort(h);
    unsigned int u = (unsigned int)hb + 0x7Fu + ((hb >> 8) & 1u);
    return (unsigned char)(u >> 8);
}
__device__ __forceinline__ float e5m2f(unsigned int b) {
    return __half2float(__ushort_as_half((ushort)(b << 8)));
}

#define NEGV (-3.4028234663852886e38f)
#define SCALE 0.17677669529663687f

// ---------------- K0: W -> bf16, transposed (N-major, K-contiguous) --------
__global__ __launch_bounds__(256) void k_wconv(
    const float* __restrict__ Wqkv, const float* __restrict__ Wg,
    const float* __restrict__ Wout, ushort* __restrict__ WT,
    ushort* __restrict__ WoT)
{
    int idx = blockIdx.x * 256 + threadIdx.x;   // grid 320 -> 81920
    if (idx < 65536) {
        int n = idx >> 7, k = idx & 127;
        float v = (n < 384) ? Wqkv[(size_t)k * 384 + n]
                            : Wg[(size_t)k * 128 + (n - 384)];
        WT[idx] = f2bf(v);
    } else {
        int i2 = idx - 65536;
        int c = i2 >> 7, e = i2 & 127;
        WoT[i2] = f2bf(Wout[(size_t)e * 128 + c]);
    }
}

// ---------------- K1: LayerNorm -> x bf16, + bias GEMV (fp8, frag-ordered) -
__global__ __launch_bounds__(256) void k_ln(
    const float* __restrict__ edges, const float* __restrict__ gamma,
    const float* __restrict__ beta,  const float* __restrict__ Wb,
    ushort* __restrict__ Xb, unsigned char* __restrict__ Bo8)
{
    __shared__ float xs[64][132];
    const int tid = threadIdx.x, w = tid >> 6, lane = tid & 63;
    const int p0 = blockIdx.x * 64;
    const float g0 = gamma[lane], g1 = gamma[lane + 64];
    const float b0 = beta[lane],  b1 = beta[lane + 64];
    for (int pp = 0; pp < 16; ++pp) {
        const int row = w * 16 + pp;
        const float* ep = edges + (size_t)(p0 + row) * DD;
        float e0 = ep[lane], e1 = ep[lane + 64];
        float s = e0 + e1;
        #pragma unroll
        for (int off = 1; off < 64; off <<= 1) s += __shfl_xor(s, off);
        float mu = s * 0.0078125f;
        float d0 = e0 - mu, d1 = e1 - mu;
        float ss = d0 * d0 + d1 * d1;
        #pragma unroll
        for (int off = 1; off < 64; off <<= 1) ss += __shfl_xor(ss, off);
        float rstd = rsqrtf(ss * 0.0078125f + 1e-5f);
        xs[row][lane]      = d0 * rstd * g0 + b0;
        xs[row][lane + 64] = d1 * rstd * g1 + b1;
    }
    __syncthreads();
    #pragma unroll
    for (int pass = 0; pass < 8; ++pass) {
        int idx = pass * 256 + tid;
        int r = idx >> 5, c = (idx & 31) * 4;
        ushort4 o;
        o.x = f2bf(xs[r][c + 0]); o.y = f2bf(xs[r][c + 1]);
        o.z = f2bf(xs[r][c + 2]); o.w = f2bf(xs[r][c + 3]);
        *reinterpret_cast<ushort4*>(&Xb[(size_t)(p0 + r) * DD + c]) = o;
    }
    // bias = x @ Wb, fp8 e5m2, fragment-ordered: [h][(j*4+lg)*16+fn]*4+r
    {
        const int r = tid >> 2, hh = tid & 3;
        float acc = 0.f;
        for (int e = 0; e < DD; ++e) acc += xs[r][e] * Wb[e * 4 + hh];
        const int p = p0 + r;
        const int j = p >> 8, k = p & 255;
        const int fn = k >> 4, lgk = (k >> 2) & 3, rr = k & 3;
        Bo8[(size_t)hh * 65536 + (((size_t)j * 4 + lgk) * 16 + fn) * 4 + rr] = f2e5m2(acc);
    }
}

// ---------------- K2: x @ [Wqkv|Wg] via MFMA; head-blocked outputs ---------
__global__ __launch_bounds__(256) void k_gemm_qkvg(
    const ushort* __restrict__ Xb, const ushort* __restrict__ WT,
    const float* __restrict__ bg,
    ushort* __restrict__ Qo, ushort* __restrict__ Ko,
    ushort* __restrict__ Vo, ushort* __restrict__ Go)
{
    __shared__ __align__(16) ushort As[64][136];
    __shared__ __align__(16) ushort Bs[128][136];
    const int tid = threadIdx.x;
    const int p0 = blockIdx.x * 64;
    #pragma unroll
    for (int it = 0; it < 4; ++it) {
        int idx = it * 256 + tid;
        int r = idx >> 4, c = (idx & 15) * 8;
        *reinterpret_cast<uint4*>(&As[r][c]) =
            *reinterpret_cast<const uint4*>(&Xb[(size_t)(p0 + r) * DD + c]);
    }
    const int w = tid >> 6, lane = tid & 63;
    const int wm = w >> 1, wn = w & 1;
    const int lr = lane & 15, lg = lane >> 4;
    const f32x4 zz = {0.f, 0.f, 0.f, 0.f};

    for (int seg = 0; seg < 4; ++seg) {
        const int n0 = seg * 128;
        __syncthreads();
        #pragma unroll
        for (int it = 0; it < 8; ++it) {
            int idx = it * 256 + tid;
            int r = idx >> 4, c = (idx & 15) * 8;
            *reinterpret_cast<uint4*>(&Bs[r][c]) =
                *reinterpret_cast<const uint4*>(&WT[(size_t)(n0 + r) * DD + c]);
        }
        __syncthreads();
        f32x4 acc[2][4];
        #pragma unroll
        for (int m = 0; m < 2; ++m)
            #pragma unroll
            for (int n = 0; n < 4; ++n) acc[m][n] = zz;
        #pragma unroll
        for (int kk = 0; kk < 4; ++kk) {
            bf16x8 a0 = *reinterpret_cast<const bf16x8*>(&As[wm * 32 + lr][kk * 32 + lg * 8]);
            bf16x8 a1 = *reinterpret_cast<const bf16x8*>(&As[wm * 32 + 16 + lr][kk * 32 + lg * 8]);
            #pragma unroll
            for (int n = 0; n < 4; ++n) {
                bf16x8 b = *reinterpret_cast<const bf16x8*>(&Bs[wn * 64 + n * 16 + lr][kk * 32 + lg * 8]);
                acc[0][n] = mfma16(a0, b, acc[0][n]);
                acc[1][n] = mfma16(a1, b, acc[1][n]);
            }
        }
        #pragma unroll
        for (int n = 0; n < 4; ++n) {
            const int cc = wn * 64 + n * 16 + lr;
            const int hh = cc >> 5, dh = cc & 31;
            const float bgv = (seg == 3) ? bg[cc] : 0.f;
            #pragma unroll
            for (int m = 0; m < 2; ++m) {
                #pragma unroll
                for (int r = 0; r < 4; ++r) {
                    const int p = p0 + wm * 32 + m * 16 + lg * 4 + r;
                    const float v = acc[m][n][r];
                    const size_t off = (size_t)hh * HSTR + (size_t)p * 32 + dh;
                    if (seg == 0)      Qo[off] = f2bf(v * SCALE);
                    else if (seg == 1) Ko[off] = f2bf(v);
                    else if (seg == 2) Vo[off] = f2bf(v);
                    else Go[off] = f2bf(1.0f / (1.0f + __expf(-(v + bgv))));
                }
            }
        }
    }
}

// ---------------- K3: attention; grid 512, 2 i-units/block, same head ------
// h = bid&3 (two XCDs per head), i = 2*(bid>>2) + un. LDS 46KB -> all
// 512 blocks co-resident (2/CU), no dispatch tail.
__global__ __launch_bounds__(256, 2) void k_attn7(
    const ushort* __restrict__ Qw, const ushort* __restrict__ Kw,
    const ushort* __restrict__ Vw, const unsigned char* __restrict__ Bo8,
    const int* __restrict__ mask, ushort* __restrict__ OPre)
{
    __shared__ __align__(16) ushort Ks[256][40];   // K rows: 20.0KB
    __shared__ __align__(16) ushort Vt[32][268];   // V^T [d][k]: 16.75KB
    __shared__ __align__(16) ushort Pl[4][16][72]; // per-wave P chunk: 9.2KB
    const int tid = threadIdx.x, w = tid >> 6, lane = tid & 63;
    const int lr = lane & 15, lg = lane >> 4;
    const int h = blockIdx.x & 3;
    const int i0 = (blockIdx.x >> 2) << 1;
    const unsigned char* bias_h = Bo8 + (size_t)h * 65536;
    const f32x4 zz = {0.f, 0.f, 0.f, 0.f};

    for (int un = 0; un < 2; ++un) {
        const int i = i0 + un;
        const int ib = i * NP;
        const size_t base = (size_t)h * HSTR + (size_t)ib * 32;   // + k*32 + dh
        if (un) __syncthreads();   // all waves done with prev unit's LDS
        // stage K rows (contiguous 16KB)
        #pragma unroll
        for (int it = 0; it < 4; ++it) {
            int idx = it * 256 + tid;
            int r = idx >> 2, c = (idx & 3) * 8;
            *reinterpret_cast<uint4*>(&Ks[r][c]) =
                *reinterpret_cast<const uint4*>(&Kw[base + (size_t)r * 32 + c]);
        }
        // stage V^T
        #pragma unroll
        for (int it = 0; it < 8; ++it) {
            int idx = it * 256 + tid;
            int d = idx & 31, k4 = (idx >> 5) * 4;
            ushort4 v;
            v.x = Vw[base + (size_t)(k4 + 0) * 32 + d];
            v.y = Vw[base + (size_t)(k4 + 1) * 32 + d];
            v.z = Vw[base + (size_t)(k4 + 2) * 32 + d];
            v.w = Vw[base + (size_t)(k4 + 3) * 32 + d];
            *reinterpret_cast<ushort4*>(&Vt[d][k4]) = v;
        }
        __syncthreads();

        for (int jt = 0; jt < 4; ++jt) {
            const int jb = jt * 64 + w * 16;
            const int jq = jb + lr;             // this lane's softmax row
            bf16x8 q = *reinterpret_cast<const bf16x8*>(&Qw[base + (size_t)jq * 32 + lg * 8]);
            // bias: 64 contiguous bytes per lane (fragment-ordered fp8)
            const unsigned char* bp = bias_h + ((size_t)jq * 4 + lg) * 64;
            union { uint4 q4[4]; unsigned int uw[16]; } bu;
            bu.q4[0] = *reinterpret_cast<const uint4*>(bp);
            bu.q4[1] = *reinterpret_cast<const uint4*>(bp + 16);
            bu.q4[2] = *reinterpret_cast<const uint4*>(bp + 32);
            bu.q4[3] = *reinterpret_cast<const uint4*>(bp + 48);
            f32x4 s[16];
            #pragma unroll
            for (int fn = 0; fn < 16; ++fn) {
                const unsigned int ww = bu.uw[fn];
                f32x4 sv;
                sv[0] = e5m2f(ww & 0xffu);
                sv[1] = e5m2f((ww >> 8) & 0xffu);
                sv[2] = e5m2f((ww >> 16) & 0xffu);
                sv[3] = e5m2f(ww >> 24);
                s[fn] = sv;
            }
            #pragma unroll
            for (int fn = 0; fn < 16; ++fn) {
                bf16x8 a = *reinterpret_cast<const bf16x8*>(&Ks[fn * 16 + lr][lg * 8]);
                s[fn] = mfma16(a, q, s[fn]);    // S^T[k][j]
            }
            // softmax over k for row jq (4-lane group: xor 16, 32)
            float mx = -3.402823466e38f;
            #pragma unroll
            for (int fn = 0; fn < 16; ++fn) {
                float m01 = fmaxf(s[fn][0], s[fn][1]);
                float m23 = fmaxf(s[fn][2], s[fn][3]);
                mx = fmaxf(mx, fmaxf(m01, m23));
            }
            mx = fmaxf(mx, __shfl_xor(mx, 16));
            mx = fmaxf(mx, __shfl_xor(mx, 32));
            float sum = 0.f;
            #pragma unroll
            for (int fn = 0; fn < 16; ++fn) {
                #pragma unroll
                for (int r = 0; r < 4; ++r) {
                    float e = __expf(s[fn][r] - mx);
                    s[fn][r] = e; sum += e;
                }
            }
            sum += __shfl_xor(sum, 16);
            sum += __shfl_xor(sum, 32);
            const bool masked = (mask[ib + jq] == 0);
            const float iv = masked ? 1.0f : (1.0f / sum);

            // PV in 4 chunks of 64 keys; swapped operands -> O[j=jq][d=4lg+r]
            f32x4 o0 = zz, o1 = zz;
            #pragma unroll
            for (int c = 0; c < 4; ++c) {
                #pragma unroll
                for (int fnl = 0; fnl < 4; ++fnl) {
                    const int fn = c * 4 + fnl;
                    unsigned int w0 = packbf(s[fn][0], s[fn][1]);
                    unsigned int w1 = packbf(s[fn][2], s[fn][3]);
                    if (masked) { w0 = 0x3B803B80u; w1 = 0x3B803B80u; }  // 1/256
                    uint2 pw; pw.x = w0; pw.y = w1;
                    *reinterpret_cast<uint2*>(&Pl[w][lr][fnl * 16 + 4 * lg]) = pw;
                }
                #pragma unroll
                for (int ks = 0; ks < 2; ++ks) {
                    bf16x8 pa = *reinterpret_cast<const bf16x8*>(&Pl[w][lr][ks * 32 + lg * 8]);
                    bf16x8 v0 = *reinterpret_cast<const bf16x8*>(&Vt[lr][c * 64 + ks * 32 + lg * 8]);
                    bf16x8 v1 = *reinterpret_cast<const bf16x8*>(&Vt[16 + lr][c * 64 + ks * 32 + lg * 8]);
                    o0 = mfma16(v0, pa, o0);
                    o1 = mfma16(v1, pa, o1);
                }
            }
            // epilogue: lane owns row jq; O[jq][4lg+r] / O[jq][16+4lg+r]
            const size_t off = base + (size_t)jq * 32;
            uint2 u0, u1;
            u0.x = packbf(o0[0] * iv, o0[1] * iv);
            u0.y = packbf(o0[2] * iv, o0[3] * iv);
            u1.x = packbf(o1[0] * iv, o1[1] * iv);
            u1.y = packbf(o1[2] * iv, o1[3] * iv);
            *reinterpret_cast<uint2*>(&OPre[off + 4 * lg])      = u0;
            *reinterpret_cast<uint2*>(&OPre[off + 16 + 4 * lg]) = u1;
        }
    }
}

// ---------------- K4: out = (g .* OPre) @ Wout + bout (gating fused) -------
__device__ __forceinline__ unsigned int gate2(unsigned int o2, unsigned int g2, bool mk) {
    float a0 = bf2f((ushort)(o2 & 0xffffu)), a1 = bf2f((ushort)(o2 >> 16));
    float g0 = mk ? NEGV : bf2f((ushort)(g2 & 0xffffu));
    float g1 = mk ? NEGV : bf2f((ushort)(g2 >> 16));
    return packbf(a0 * g0, a1 * g1);
}

__global__ __launch_bounds__(256) void k_gemm_out(
    const ushort* __restrict__ OPre, const ushort* __restrict__ Gw,
    const int* __restrict__ mask, const ushort* __restrict__ WoT,
    const float* __restrict__ bout, float* __restrict__ out)
{
    __shared__ __align__(16) ushort As[64][136];
    __shared__ __align__(16) ushort Bs[128][136];
    const int tid = threadIdx.x;
    const int p0 = blockIdx.x * 64;
    #pragma unroll
    for (int it = 0; it < 4; ++it) {
        int idx = it * 256 + tid;
        int r = idx >> 4, c = (idx & 15) * 8;
        int hh = c >> 5, dq = c & 31;
        const int p = p0 + r;
        const size_t go = (size_t)hh * HSTR + (size_t)p * 32 + dq;
        uint4 ov = *reinterpret_cast<const uint4*>(&OPre[go]);
        uint4 gv = *reinterpret_cast<const uint4*>(&Gw[go]);
        const bool mk = (mask[p] == 0);
        uint4 rs;
        rs.x = gate2(ov.x, gv.x, mk);
        rs.y = gate2(ov.y, gv.y, mk);
        rs.z = gate2(ov.z, gv.z, mk);
        rs.w = gate2(ov.w, gv.w, mk);
        *reinterpret_cast<uint4*>(&As[r][c]) = rs;
    }
    #pragma unroll
    for (int it = 0; it < 8; ++it) {
        int idx = it * 256 + tid;
        int r = idx >> 4, c = (idx & 15) * 8;
        *reinterpret_cast<uint4*>(&Bs[r][c]) =
            *reinterpret_cast<const uint4*>(&WoT[(size_t)r * DD + c]);
    }
    __syncthreads();
    const int w = tid >> 6, lane = tid & 63;
    const int wm = w >> 1, wn = w & 1;
    const int lr = lane & 15, lg = lane >> 4;
    const f32x4 zz = {0.f, 0.f, 0.f, 0.f};
    f32x4 acc[2][4];
    #pragma unroll
    for (int m = 0; m < 2; ++m)
        #pragma unroll
        for (int n = 0; n < 4; ++n) acc[m][n] = zz;
    #pragma unroll
    for (int kk = 0; kk < 4; ++kk) {
        bf16x8 a0 = *reinterpret_cast<const bf16x8*>(&As[wm * 32 + lr][kk * 32 + lg * 8]);
        bf16x8 a1 = *reinterpret_cast<const bf16x8*>(&As[wm * 32 + 16 + lr][kk * 32 + lg * 8]);
        #pragma unroll
        for (int n = 0; n < 4; ++n) {
            bf16x8 b = *reinterpret_cast<const bf16x8*>(&Bs[wn * 64 + n * 16 + lr][kk * 32 + lg * 8]);
            acc[0][n] = mfma16(a0, b, acc[0][n]);
            acc[1][n] = mfma16(a1, b, acc[1][n]);
        }
    }
    #pragma unroll
    for (int n = 0; n < 4; ++n) {
        const int c = wn * 64 + n * 16 + lr;
        const float bo = bout[c];
        #pragma unroll
        for (int m = 0; m < 2; ++m) {
            #pragma unroll
            for (int r = 0; r < 4; ++r) {
                const int p = p0 + wm * 32 + m * 16 + lg * 4 + r;
                out[(size_t)p * DD + c] = acc[m][n][r] + bo;
            }
        }
    }
}

extern "C" void kernel_launch(void* const* d_in, const int* in_sizes, int n_in,
                              void* d_out, int out_size, void* d_ws, size_t ws_size,
                              hipStream_t stream) {
    const float* edges = (const float*)d_in[0];
    const int*   mask  = (const int*)d_in[1];
    const float* gamma = (const float*)d_in[2];
    const float* beta  = (const float*)d_in[3];
    const float* Wqkv  = (const float*)d_in[4];
    const float* Wb    = (const float*)d_in[5];
    const float* Wg    = (const float*)d_in[6];
    const float* bg    = (const float*)d_in[7];
    const float* Wout  = (const float*)d_in[8];
    const float* bout  = (const float*)d_in[9];
    float* out = (float*)d_out;

    char* ws = (char*)d_ws;
    ushort* Xb  = (ushort*)(ws);                               // 16 MiB
    ushort* Qw  = (ushort*)(ws + 1u * 16777216u);              // 16 MiB (head-blocked)
    ushort* Kw  = (ushort*)(ws + 2u * 16777216u);
    ushort* Vw  = (ushort*)(ws + 3u * 16777216u);
    ushort* Gw  = (ushort*)(ws + 4u * 16777216u);
    unsigned char* Bo8 = (unsigned char*)(ws + 5u * 16777216u);        // 256 KiB fp8
    ushort* WT  = (ushort*)(ws + 5u * 16777216u + 262144u);            // 128 KiB
    ushort* WoT = (ushort*)(ws + 5u * 16777216u + 262144u + 131072u);  // 32 KiB
    ushort* OPre = Xb;   // Xb dead after k_gemm_qkvg; OPre is head-blocked

    k_wconv<<<dim3(320), dim3(256), 0, stream>>>(Wqkv, Wg, Wout, WT, WoT);
    k_ln<<<dim3(1024), dim3(256), 0, stream>>>(edges, gamma, beta, Wb, Xb, Bo8);
    k_gemm_qkvg<<<dim3(1024), dim3(256), 0, stream>>>(Xb, WT, bg, Qw, Kw, Vw, Gw);
    k_attn7<<<dim3(512), dim3(256), 0, stream>>>(Qw, Kw, Vw, Bo8, mask, OPre);
    k_gemm_out<<<dim3(1024), dim3(256), 0, stream>>>(OPre, Gw, mask, WoT, bout, out);
}